// Round 10
// baseline (273.393 us; speedup 1.0000x reference)
//
#include <hip/hip_runtime.h>

#define NNODE 2048
#define NBATCH 32

typedef __attribute__((ext_vector_type(4))) float f32x4;
typedef __attribute__((ext_vector_type(8))) __bf16 bf16x8;
typedef __attribute__((ext_vector_type(4))) __bf16 bf16x4;

__device__ __forceinline__ void gload16(const void* g, void* lds) {
  __builtin_amdgcn_global_load_lds(
      (const __attribute__((address_space(1))) unsigned int*)g,
      (__attribute__((address_space(3))) unsigned int*)lds, 16, 0, 0);
}

// ---------------------------------------------------------------------------
// Merged: prep_e (blocks 0..127) + prep_w (blocks 128..223)
__global__ __launch_bounds__(256) void prep_ew(const float* __restrict__ E1,
                                               const float* __restrict__ E2,
                                               const float* __restrict__ Wz,
                                               const float* __restrict__ Wr,
                                               const float* __restrict__ Wc,
                                               const float* __restrict__ wpre,
                                               const float* __restrict__ wadp,
                                               __bf16* __restrict__ E1p,
                                               __bf16* __restrict__ E2p,
                                               __bf16* __restrict__ Wzrt,
                                               __bf16* __restrict__ Wct) {
  if (blockIdx.x < 128) {
    int idx = blockIdx.x * 256 + threadIdx.x;  // 0..32767
    int cq = idx & 3;
    int n = (idx >> 2) & 2047;
    int h = idx >> 13;
    const float4 q1 = *(const float4*)(E1 + (size_t)(n * 4 + h) * 16 + cq * 4);
    const float4 q2 = *(const float4*)(E2 + (size_t)(n * 4 + h) * 16 + cq * 4);
    size_t o = ((size_t)h * NNODE + n) * 32 + cq * 4;
    E1p[o + 0] = (__bf16)q1.x; E1p[o + 1] = (__bf16)q1.y;
    E1p[o + 2] = (__bf16)q1.z; E1p[o + 3] = (__bf16)q1.w;
    E2p[o + 0] = (__bf16)q2.x; E2p[o + 1] = (__bf16)q2.y;
    E2p[o + 2] = (__bf16)q2.z; E2p[o + 3] = (__bf16)q2.w;
    size_t oz = o + 16;
    E1p[oz + 0] = (__bf16)0.f; E1p[oz + 1] = (__bf16)0.f;
    E1p[oz + 2] = (__bf16)0.f; E1p[oz + 3] = (__bf16)0.f;
    E2p[oz + 0] = (__bf16)0.f; E2p[oz + 1] = (__bf16)0.f;
    E2p[oz + 2] = (__bf16)0.f; E2p[oz + 3] = (__bf16)0.f;
  } else {
    int idx = (blockIdx.x - 128) * 256 + threadIdx.x;  // 0 .. 128*192-1
    int rr = idx / 192, k = idx % 192;
    float s = 2.f * (*wpre) + (*wadp);
    float sc = (k < 64) ? s : 1.f;
    float vz = (rr < 64) ? Wz[(size_t)k * 64 + rr] : Wr[(size_t)k * 64 + rr - 64];
    Wzrt[idx] = (__bf16)(vz * sc);
    float vc = (rr < 64) ? Wc[(size_t)k * 64 + rr] * sc : 0.f;
    Wct[idx] = (__bf16)vc;
  }
}

// ---------------------------------------------------------------------------
// SC[h][w][v] = relu(E1p_h @ E2p_h^T)/4, bf16. Single K=32 MFMA step.
__global__ __launch_bounds__(256) void score_gemm(const __bf16* __restrict__ E1p,
                                                  const __bf16* __restrict__ E2p,
                                                  __bf16* __restrict__ SC) {
  __shared__ __bf16 As[128 * 32];
  __shared__ __bf16 Bs[128 * 32];
  const int tid = threadIdx.x;
  const int wave = tid >> 6, lane = tid & 63;
  const int wr = wave >> 1, wc = wave & 1;
  const int h = blockIdx.z;
  const int m0 = blockIdx.x * 128, n0 = blockIdx.y * 128;
  const __bf16* A = E1p + (size_t)h * NNODE * 32;
  const __bf16* Bt = E2p + (size_t)h * NNODE * 32;
  const int rowA = tid >> 2;
  const int colb = (tid & 3) * 16;
  gload16((const char*)(A + (size_t)(m0 + rowA) * 32) + colb, (char*)As + wave * 1024);
  gload16((const char*)(A + (size_t)(m0 + rowA + 64) * 32) + colb, (char*)As + 4096 + wave * 1024);
  gload16((const char*)(Bt + (size_t)(n0 + rowA) * 32) + colb, (char*)Bs + wave * 1024);
  gload16((const char*)(Bt + (size_t)(n0 + rowA + 64) * 32) + colb, (char*)Bs + 4096 + wave * 1024);
  __syncthreads();

  f32x4 acc[4][4] = {};
  bf16x8 af[4], bfr[4];
#pragma unroll
  for (int mi = 0; mi < 4; ++mi)
    af[mi] = *(const bf16x8*)((const char*)As +
             ((wr * 64 + mi * 16 + (lane & 15)) * 64 + (lane >> 4) * 16));
#pragma unroll
  for (int ni = 0; ni < 4; ++ni)
    bfr[ni] = *(const bf16x8*)((const char*)Bs +
             ((wc * 64 + ni * 16 + (lane & 15)) * 64 + (lane >> 4) * 16));
#pragma unroll
  for (int mi = 0; mi < 4; ++mi)
#pragma unroll
    for (int ni = 0; ni < 4; ++ni)
      acc[mi][ni] = __builtin_amdgcn_mfma_f32_16x16x32_bf16(af[mi], bfr[ni],
                                                            acc[mi][ni], 0, 0, 0);

  const int crow = (lane >> 4) * 4;
  const int ccol = lane & 15;
#pragma unroll
  for (int mi = 0; mi < 4; ++mi)
#pragma unroll
    for (int ni = 0; ni < 4; ++ni) {
      int r0 = m0 + wr * 64 + mi * 16 + crow;
      int cc = n0 + wc * 64 + ni * 16 + ccol;
#pragma unroll
      for (int r = 0; r < 4; ++r) {
        float val = fmaxf(acc[mi][ni][r], 0.f) * 0.25f;
        SC[((size_t)h * NNODE + r0 + r) * NNODE + cc] = (__bf16)val;
      }
    }
}

// ---------------------------------------------------------------------------
// Row softmax over v: one wave per row of SC [8192 x 2048] bf16 -> adjh bf16
__global__ __launch_bounds__(256) void softmax_rows(const __bf16* __restrict__ SC,
                                                    __bf16* __restrict__ adjh) {
  const int tid = threadIdx.x;
  const int wave = tid >> 6, lane = tid & 63;
  const size_t row = (size_t)blockIdx.x * 4 + wave;
  const __bf16* src = SC + row * NNODE;
  __bf16* dst = adjh + row * NNODE;
  float v[32];
  float mx = 0.f;
#pragma unroll
  for (int j = 0; j < 4; ++j) {
    bf16x8 q = *(const bf16x8*)(src + j * 512 + lane * 8);
#pragma unroll
    for (int i = 0; i < 8; ++i) {
      float f = (float)q[i];
      v[j * 8 + i] = f;
      mx = fmaxf(mx, f);
    }
  }
#pragma unroll
  for (int o = 32; o > 0; o >>= 1) mx = fmaxf(mx, __shfl_xor(mx, o));
  float s = 0.f;
#pragma unroll
  for (int i = 0; i < 32; ++i) {
    v[i] = __expf(v[i] - mx);
    s += v[i];
  }
#pragma unroll
  for (int o = 32; o > 0; o >>= 1) s += __shfl_xor(s, o);
  float inv = 1.f / s;
#pragma unroll
  for (int j = 0; j < 4; ++j) {
    bf16x8 q;
#pragma unroll
    for (int i = 0; i < 8; ++i) q[i] = (__bf16)(v[j * 8 + i] * inv);
    *(bf16x8*)(dst + j * 512 + lane * 8) = q;
  }
}

// ---------------------------------------------------------------------------
// Fused adjacency prep: ADJ bf16, w-scaled ADJT, M1 accum. (R8-verified)
__global__ __launch_bounds__(256) void prep_adj(const float* __restrict__ A1,
                                                const float* __restrict__ A2,
                                                __bf16* __restrict__ ADJ,
                                                __bf16* __restrict__ ADJT,
                                                __bf16* __restrict__ M1,
                                                const float* __restrict__ wpre,
                                                const float* __restrict__ wadp) {
  const int r0 = blockIdx.x * 64, c0 = blockIdx.y * 64;
  const int tid = threadIdx.x;
  const size_t NN2 = (size_t)NNODE * NNODE;
  const float wp = *wpre, wa = *wadp * 0.25f;
  __shared__ float t[64][65];
  const int vr = tid >> 2, cg = (tid & 3) * 16;
  float m1acc[16] = {};

  for (int z = 0; z < 6; ++z) {
    const float wz = (z < 2) ? wp : wa;
    float vv[16];
    if (z < 2) {
      const float* src = (z == 0 ? A1 : A2) + (size_t)(r0 + vr) * NNODE + c0 + cg;
#pragma unroll
      for (int j = 0; j < 4; ++j) {
        float4 q = ((const float4*)src)[j];
        vv[j * 4 + 0] = q.x; vv[j * 4 + 1] = q.y;
        vv[j * 4 + 2] = q.z; vv[j * 4 + 3] = q.w;
      }
      __bf16* q = ADJ + (size_t)z * NN2 + (size_t)(r0 + vr) * NNODE + c0 + cg;
      bf16x8 o0, o1;
#pragma unroll
      for (int i = 0; i < 8; ++i) { o0[i] = (__bf16)vv[i]; o1[i] = (__bf16)vv[8 + i]; }
      ((bf16x8*)q)[0] = o0;
      ((bf16x8*)q)[1] = o1;
    } else {
      const __bf16* p = ADJ + (size_t)z * NN2 + (size_t)(r0 + vr) * NNODE + c0 + cg;
      bf16x8 q0 = ((const bf16x8*)p)[0];
      bf16x8 q1 = ((const bf16x8*)p)[1];
#pragma unroll
      for (int i = 0; i < 8; ++i) { vv[i] = (float)q0[i]; vv[8 + i] = (float)q1[i]; }
    }
#pragma unroll
    for (int i = 0; i < 16; ++i) {
      m1acc[i] += wz * vv[i];
      t[vr][cg + i] = vv[i];
    }
    __syncthreads();
#pragma unroll
    for (int jr = 0; jr < 16; ++jr) {
      int c = jr * 4 + (tid >> 6);
      int v = tid & 63;
      ADJT[(size_t)z * NN2 + (size_t)(c0 + c) * NNODE + r0 + v] = (__bf16)(wz * t[v][c]);
    }
    __syncthreads();
  }
  __bf16* q = M1 + (size_t)(r0 + vr) * NNODE + c0 + cg;
  bf16x8 o0, o1;
#pragma unroll
  for (int i = 0; i < 8; ++i) { o0[i] = (__bf16)m1acc[i]; o1[i] = (__bf16)m1acc[8 + i]; }
  ((bf16x8*)q)[0] = o0;
  ((bf16x8*)q)[1] = o1;
}

// ---------------------------------------------------------------------------
// x f32 [B,N,64] -> XT bf16 [B*64, N] and xbf bf16 [B*N,64]
__global__ __launch_bounds__(256) void transpose_x(const float* __restrict__ x,
                                                   __bf16* __restrict__ XT,
                                                   __bf16* __restrict__ xbf) {
  const int b = blockIdx.y, v0 = blockIdx.x * 64;
  const int tid = threadIdx.x;
  __shared__ float t[64][65];
  const int vr = tid >> 2, c0 = (tid & 3) * 16;
  const float* src = x + ((size_t)b * NNODE + v0 + vr) * 64 + c0;
  __bf16* xb = xbf + ((size_t)b * NNODE + v0 + vr) * 64 + c0;
#pragma unroll
  for (int j = 0; j < 4; ++j) {
    float4 q = ((const float4*)src)[j];
    t[vr][c0 + j * 4 + 0] = q.x;
    t[vr][c0 + j * 4 + 1] = q.y;
    t[vr][c0 + j * 4 + 2] = q.z;
    t[vr][c0 + j * 4 + 3] = q.w;
    xb[j * 4 + 0] = (__bf16)q.x;
    xb[j * 4 + 1] = (__bf16)q.y;
    xb[j * 4 + 2] = (__bf16)q.z;
    xb[j * 4 + 3] = (__bf16)q.w;
  }
  __syncthreads();
#pragma unroll
  for (int jr = 0; jr < 16; ++jr) {
    int c = jr * 4 + (tid >> 6);
    int v = tid & 63;
    XT[((size_t)b * 64 + c) * NNODE + v0 + v] = (__bf16)t[v][c];
  }
}

// rx bf16 [B*N,64] -> XT bf16 [B*64, N]
__global__ __launch_bounds__(256) void transpose_rx(const __bf16* __restrict__ rx,
                                                    __bf16* __restrict__ XT) {
  const int b = blockIdx.y, v0 = blockIdx.x * 64;
  const int tid = threadIdx.x;
  __shared__ float t[64][65];
  const int vr = tid >> 2, c0 = (tid & 3) * 16;
  const __bf16* src = rx + ((size_t)b * NNODE + v0 + vr) * 64 + c0;
  bf16x8 q0 = ((const bf16x8*)src)[0];
  bf16x8 q1 = ((const bf16x8*)src)[1];
#pragma unroll
  for (int i = 0; i < 8; ++i) {
    t[vr][c0 + i] = (float)q0[i];
    t[vr][c0 + 8 + i] = (float)q1[i];
  }
  __syncthreads();
#pragma unroll
  for (int jr = 0; jr < 16; ++jr) {
    int c = jr * 4 + (tid >> 6);
    int v = tid & 63;
    XT[((size_t)b * 64 + c) * NNODE + v0 + v] = (__bf16)t[v][c];
  }
}

// ---------------------------------------------------------------------------
// Shared GEMM machinery (R7-verified swizzle/sync): 128x128, BK=64, 4 waves,
// 2 blocks/CU, counted vmcnt(8). R10: saddr-form addressing (uniform running
// tile offset + invariant 32-bit lane offsets) and MFMA-before-vmcnt reorder
// (MFMA is register-only; overlaps the load drain).
#define VMCNT0() asm volatile("s_waitcnt vmcnt(0)" ::: "memory")
#define VMCNT8() asm volatile("s_waitcnt vmcnt(8)" ::: "memory")
#define LGKMCNT0() asm volatile("s_waitcnt lgkmcnt(0)" ::: "memory")
#define BARRIER() asm volatile("s_barrier" ::: "memory")

// Fused-squares: M2part[zh] = sum_{z in half} ADJ_z @ ADJT_z^T (ADJT w-scaled),
// f32 partials. 96 K-tiles/block.
__global__ __launch_bounds__(256, 2) void gemm_sq(const __bf16* __restrict__ ADJ,
                                                  const __bf16* __restrict__ ADJT,
                                                  float* __restrict__ M2part) {
  extern __shared__ char smem[];  // 65536 B
  const int tid = threadIdx.x;
  const int w = tid >> 6, l = tid & 63;
  const int wr = w >> 1, wc = w & 1;
  const size_t NN2 = (size_t)NNODE * NNODE;
  const size_t NN2B2 = NN2 * 2;
  int lin = blockIdx.x + 16 * blockIdx.y + 256 * blockIdx.z;
  int nlin = (lin & 7) * 64 + (lin >> 3);
  const int m0 = (nlin & 15) * 128, n0 = ((nlin >> 4) & 15) * 128;
  const int zh = nlin >> 8;
  const int zb = zh * 3;
  float* Cp = M2part + (size_t)zh * NN2;
  const int NTT = 96;  // 3 z * 32 K-tiles

#define AREG(d) (smem + (d) * 16384)
#define BREG(d) (smem + 32768 + (d) * 16384)

  int aoff[4][2], boff[4][2];
#pragma unroll
  for (int mi = 0; mi < 4; ++mi)
#pragma unroll
    for (int ks = 0; ks < 2; ++ks) {
      int rh = mi * 32 + wr * 16 + (l & 15);
      int lo = rh * 128 + ks * 64 + ((l >> 4) * 16);
      aoff[mi][ks] = lo ^ ((rh & 7) << 4);
    }
#pragma unroll
  for (int j = 0; j < 4; ++j)
#pragma unroll
    for (int ks = 0; ks < 2; ++ks) {
      int rh = j * 32 + wc * 16 + (l & 15);
      int lo = rh * 128 + ks * 64 + ((l >> 4) * 16);
      boff[j][ks] = lo ^ ((rh & 7) << 4);
    }

  const int sg_row = w * 8 + (l >> 3);
  const int sg_col = (((l & 7) ^ ((l >> 3) & 7)) << 4);
  // loop-invariant 32-bit per-lane global offsets (one per 32-row chunk)
  unsigned aLoff[4], bLoff[4];
#pragma unroll
  for (int p = 0; p < 4; ++p) {
    aLoff[p] = (unsigned)((m0 + p * 32 + sg_row) * 4096 + sg_col);
    bLoff[p] = (unsigned)((n0 + p * 32 + sg_row) * 4096 + sg_col);
  }

#define STAGEOFF(toff, region)                                                \
  do {                                                                        \
    _Pragma("unroll")                                                         \
    for (int p = 0; p < 4; ++p) {                                             \
      gload16((const char*)ADJ + (toff) + aLoff[p],                           \
              (region) + p * 4096 + w * 1024);                                \
    }                                                                         \
  } while (0)
#define STAGEOFFB(toff, region)                                               \
  do {                                                                        \
    _Pragma("unroll")                                                         \
    for (int p = 0; p < 4; ++p) {                                             \
      gload16((const char*)ADJT + (toff) + bLoff[p],                          \
              (region) + p * 4096 + w * 1024);                                \
    }                                                                         \
  } while (0)

  f32x4 acc[4][4] = {};
  bf16x8 af[4][2], bfr[4][2];

  // prologue: tiles 0,1 ; tOff then points at tile 2
  size_t tOff = (size_t)zb * NN2B2;
  STAGEOFF(tOff, AREG(0));
  STAGEOFFB(tOff, BREG(0));
  STAGEOFF(tOff + 128, AREG(1));
  STAGEOFFB(tOff + 128, BREG(1));
  tOff += 256;
  VMCNT8();
  BARRIER();

  for (int t = 0; t < NTT; ++t) {
    const int d = t & 1;
#pragma unroll
    for (int mi = 0; mi < 4; ++mi) {
      af[mi][0] = *(const bf16x8*)(AREG(d) + aoff[mi][0]);
      af[mi][1] = *(const bf16x8*)(AREG(d) + aoff[mi][1]);
    }
#pragma unroll
    for (int j = 0; j < 4; ++j) {
      bfr[j][0] = *(const bf16x8*)(BREG(d) + boff[j][0]);
      bfr[j][1] = *(const bf16x8*)(BREG(d) + boff[j][1]);
    }
    LGKMCNT0();
    BARRIER();  // all waves done reading buf[d] -> safe to overwrite
    if (t + 2 < NTT) {
      STAGEOFF(tOff, AREG(d));
      STAGEOFFB(tOff, BREG(d));
      tOff += (((t + 2) & 31) == 31) ? (NN2B2 - (size_t)31 * 128) : (size_t)128;
    }
    __builtin_amdgcn_s_setprio(1);
#pragma unroll
    for (int mi = 0; mi < 4; ++mi)
#pragma unroll
      for (int j = 0; j < 4; ++j)
#pragma unroll
        for (int ks = 0; ks < 2; ++ks)
          acc[mi][j] = __builtin_amdgcn_mfma_f32_16x16x32_bf16(af[mi][ks], bfr[j][ks],
                                                               acc[mi][j], 0, 0, 0);
    __builtin_amdgcn_s_setprio(0);
    if (t + 2 < NTT) {
      VMCNT8();  // t+1's 8 loads landed; t+2's 8 in flight
    } else if (t + 1 < NTT) {
      VMCNT0();  // tail: force t+1 landed
    }
    BARRIER();
  }

  const int crow = (l >> 4) * 4;
  const int ccol = l & 15;
#pragma unroll
  for (int mi = 0; mi < 4; ++mi)
#pragma unroll
    for (int j = 0; j < 4; ++j) {
      int r0 = m0 + mi * 32 + wr * 16 + crow;
      int cc = n0 + j * 32 + wc * 16 + ccol;
#pragma unroll
      for (int r = 0; r < 4; ++r)
        Cp[(size_t)(r0 + r) * NNODE + cc] = acc[mi][j][r];
    }
#undef STAGEOFF
#undef STAGEOFFB
#undef AREG
#undef BREG
}

// ---------------------------------------------------------------------------
// Stage GEMM with fused transposed epilogue (R9-verified epilogue):
//   C[m][n] = sum_k XT[m][k] * MM_z[n][k] -> writes S_z[(b,n),c] directly.
__global__ __launch_bounds__(256, 2) void gemm_hop1s(const __bf16* __restrict__ XT,
                                                     const __bf16* __restrict__ MMb,
                                                     __bf16* __restrict__ S1,
                                                     __bf16* __restrict__ S2) {
  extern __shared__ char smem[];  // 65536 B
  const int tid = threadIdx.x;
  const int w = tid >> 6, l = tid & 63;
  const int wr = w >> 1, wc = w & 1;
  const size_t NN2 = (size_t)NNODE * NNODE;
  int lin = blockIdx.x + 16 * blockIdx.y + 256 * blockIdx.z;
  int nlin = (lin & 7) * 64 + (lin >> 3);
  const int m0 = (nlin & 15) * 128, n0 = ((nlin >> 4) & 15) * 128;
  const int z = nlin >> 8;
  const char* Abase = (const char*)XT;
  const char* Bbase = (const char*)(MMb + (size_t)z * NN2);
  const int NT = NNODE / 64;

#define AREG(d) (smem + (d) * 16384)
#define BREG(d) (smem + 32768 + (d) * 16384)

  int aoff[4][2], boff[4][2];
#pragma unroll
  for (int mi = 0; mi < 4; ++mi)
#pragma unroll
    for (int ks = 0; ks < 2; ++ks) {
      int rh = mi * 32 + wr * 16 + (l & 15);
      int lo = rh * 128 + ks * 64 + ((l >> 4) * 16);
      aoff[mi][ks] = lo ^ ((rh & 7) << 4);
    }
#pragma unroll
  for (int j = 0; j < 4; ++j)
#pragma unroll
    for (int ks = 0; ks < 2; ++ks) {
      int rh = j * 32 + wc * 16 + (l & 15);
      int lo = rh * 128 + ks * 64 + ((l >> 4) * 16);
      boff[j][ks] = lo ^ ((rh & 7) << 4);
    }

  const int sg_row = w * 8 + (l >> 3);
  const int sg_col = (((l & 7) ^ ((l >> 3) & 7)) << 4);
  unsigned aLoff[4], bLoff[4];
#pragma unroll
  for (int p = 0; p < 4; ++p) {
    aLoff[p] = (unsigned)((m0 + p * 32 + sg_row) * 4096 + sg_col);
    bLoff[p] = (unsigned)((n0 + p * 32 + sg_row) * 4096 + sg_col);
  }

#define STAGEA(koff, region)                                                  \
  do {                                                                        \
    _Pragma("unroll")                                                         \
    for (int p = 0; p < 4; ++p)                                               \
      gload16(Abase + (koff) + aLoff[p], (region) + p * 4096 + w * 1024);     \
  } while (0)
#define STAGEB(koff, region)                                                  \
  do {                                                                        \
    _Pragma("unroll")                                                         \
    for (int p = 0; p < 4; ++p)                                               \
      gload16(Bbase + (koff) + bLoff[p], (region) + p * 4096 + w * 1024);     \
  } while (0)

  f32x4 acc[4][4] = {};
  bf16x8 af[4][2], bfr[4][2];

  size_t kOff = 0;
  STAGEA(kOff, AREG(0));
  STAGEB(kOff, BREG(0));
  STAGEA(kOff + 128, AREG(1));
  STAGEB(kOff + 128, BREG(1));
  kOff += 256;
  VMCNT8();
  BARRIER();

  for (int t = 0; t < NT; ++t) {
    const int d = t & 1;
#pragma unroll
    for (int mi = 0; mi < 4; ++mi) {
      af[mi][0] = *(const bf16x8*)(AREG(d) + aoff[mi][0]);
      af[mi][1] = *(const bf16x8*)(AREG(d) + aoff[mi][1]);
    }
#pragma unroll
    for (int j = 0; j < 4; ++j) {
      bfr[j][0] = *(const bf16x8*)(BREG(d) + boff[j][0]);
      bfr[j][1] = *(const bf16x8*)(BREG(d) + boff[j][1]);
    }
    LGKMCNT0();
    BARRIER();
    if (t + 2 < NT) {
      STAGEA(kOff, AREG(d));
      STAGEB(kOff, BREG(d));
      kOff += 128;
    }
    __builtin_amdgcn_s_setprio(1);
#pragma unroll
    for (int mi = 0; mi < 4; ++mi)
#pragma unroll
      for (int j = 0; j < 4; ++j)
#pragma unroll
        for (int ks = 0; ks < 2; ++ks)
          acc[mi][j] = __builtin_amdgcn_mfma_f32_16x16x32_bf16(af[mi][ks], bfr[j][ks],
                                                               acc[mi][j], 0, 0, 0);
    __builtin_amdgcn_s_setprio(0);
    if (t + 2 < NT) {
      VMCNT8();
    } else if (t + 1 < NT) {
      VMCNT0();
    }
    BARRIER();
  }

  // ---- epilogue (R9-verified): LDS transpose T[n][m] with slot-XOR swizzle,
  // coalesced write S_z[(b, n0+n)*64 + c].
  {
    const int crow = (l >> 4) * 4;
    const int ccol = l & 15;
    char* T = smem;  // 128 x 256 B = 32 KiB
#pragma unroll
    for (int mi = 0; mi < 4; ++mi)
#pragma unroll
      for (int j = 0; j < 4; ++j) {
        int ml = mi * 32 + wr * 16 + crow;
        int nl = j * 32 + wc * 16 + ccol;
        bf16x4 v;
#pragma unroll
        for (int r = 0; r < 4; ++r) v[r] = (__bf16)acc[mi][j][r];
        *(bf16x4*)(T + nl * 256 + ((ml * 2) ^ ((nl & 7) << 4))) = v;
      }
    __syncthreads();
    __bf16* dst = z ? S2 : S1;
    const int bA = m0 >> 6;
#pragma unroll
    for (int it = 0; it < 4; ++it) {
      int nl = (tid >> 3) + it * 32;
      int seg = tid & 7;
      int xorv = (nl & 7) << 4;
      const char* src = T + nl * 256;
      bf16x8 v0 = *(const bf16x8*)(src + ((seg * 32) ^ xorv));
      bf16x8 v1 = *(const bf16x8*)(src + ((seg * 32 + 16) ^ xorv));
      int b = bA + (seg >> 2);
      size_t o = ((size_t)b * NNODE + n0 + nl) * 64 + (seg & 3) * 16;
      *(bf16x8*)(dst + o) = v0;
      *(bf16x8*)(dst + o + 8) = v1;
    }
  }
#undef STAGEA
#undef STAGEB
#undef AREG
#undef BREG
}

// ---------------------------------------------------------------------------
// M2[i] = (bf16)(M2a[i] + M2b[i])
__global__ __launch_bounds__(256) void combine_m2(const float* __restrict__ M2p,
                                                  __bf16* __restrict__ M2) {
  const size_t NN2 = (size_t)NNODE * NNODE;
  size_t i = ((size_t)blockIdx.x * 256 + threadIdx.x) * 4;
  float4 a = *(const float4*)(M2p + i);
  float4 b = *(const float4*)(M2p + NN2 + i);
  M2[i + 0] = (__bf16)(a.x + b.x);
  M2[i + 1] = (__bf16)(a.y + b.y);
  M2[i + 2] = (__bf16)(a.z + b.z);
  M2[i + 3] = (__bf16)(a.w + b.w);
}

// ---------------------------------------------------------------------------
// Gate linear GEMM: [65536 x 192] @ Wt^T, K=192, N=128, fused epilogues.
template <int MODE>
__global__ __launch_bounds__(256) void gemm_lin(const __bf16* __restrict__ Xp,
                                                const __bf16* __restrict__ S1,
                                                const __bf16* __restrict__ S2,
                                                const __bf16* __restrict__ Wt,
                                                const float* __restrict__ b0,
                                                const float* __restrict__ b1,
                                                const float* __restrict__ wpre,
                                                const float* __restrict__ wadp,
                                                const float* __restrict__ hid,
                                                float* __restrict__ zbuf,
                                                __bf16* __restrict__ rxout,
                                                float* __restrict__ outp) {
  __shared__ __bf16 As[128 * 32];
  __shared__ __bf16 Bs[128 * 32];
  const int tid = threadIdx.x;
  const int wave = tid >> 6, lane = tid & 63;
  const int wr = wave >> 1, wc = wave & 1;
  const int m0 = blockIdx.x * 128;
  const int rowA = tid >> 2;
  const int colb = (tid & 3) * 16;
  const __bf16* srcs[3] = {Xp, S1, S2};
  char* asD0 = (char*)As + wave * 1024;
  char* asD1 = (char*)As + 4096 + wave * 1024;
  char* bsD0 = (char*)Bs + wave * 1024;
  char* bsD1 = (char*)Bs + 4096 + wave * 1024;

  f32x4 acc[4][4] = {};

#pragma unroll
  for (int kt = 0; kt < 6; ++kt) {
    const __bf16* Ab = srcs[kt >> 1];
    const char* aS0 = (const char*)(Ab + (size_t)(m0 + rowA) * 64) + (kt & 1) * 64 + colb;
    const char* aS1 = (const char*)(Ab + (size_t)(m0 + rowA + 64) * 64) + (kt & 1) * 64 + colb;
    const char* bS0 = (const char*)(Wt + (size_t)rowA * 192) + kt * 64 + colb;
    const char* bS1 = (const char*)(Wt + (size_t)(rowA + 64) * 192) + kt * 64 + colb;
    gload16(aS0, asD0);
    gload16(aS1, asD1);
    gload16(bS0, bsD0);
    gload16(bS1, bsD1);
    __syncthreads();
    bf16x8 af[4], bfr[4];
#pragma unroll
    for (int mi = 0; mi < 4; ++mi)
      af[mi] = *(const bf16x8*)((const char*)As +
               ((wr * 64 + mi * 16 + (lane & 15)) * 64 + (lane >> 4) * 16));
#pragma unroll
    for (int ni = 0; ni < 4; ++ni)
      bfr[ni] = *(const bf16x8*)((const char*)Bs +
               ((wc * 64 + ni * 16 + (lane & 15)) * 64 + (lane >> 4) * 16));
#pragma unroll
    for (int mi = 0; mi < 4; ++mi)
#pragma unroll
      for (int ni = 0; ni < 4; ++ni)
        acc[mi][ni] = __builtin_amdgcn_mfma_f32_16x16x32_bf16(af[mi], bfr[ni],
                                                              acc[mi][ni], 0, 0, 0);
    __syncthreads();
  }

  const float wp = *wpre, wa = *wadp;
  const float s = 2.f * wp + wa;
  const int crow = (lane >> 4) * 4;
  const int ccol = lane & 15;
#pragma unroll
  for (int mi = 0; mi < 4; ++mi)
#pragma unroll
    for (int ni = 0; ni < 4; ++ni) {
      int r0 = m0 + wr * 64 + mi * 16 + crow;
      int col = wc * 64 + ni * 16 + ccol;
      int cf = col & 63;
#pragma unroll
      for (int r = 0; r < 4; ++r) {
        int row = r0 + r;
        float g = acc[mi][ni][r];
        if (MODE == 0) {
          if (col < 64) {
            g += s * b0[cf];
            zbuf[(size_t)row * 64 + cf] = 1.f / (1.f + __expf(-g));
          } else {
            g += s * b1[cf];
            float rv = 1.f / (1.f + __expf(-g));
            rxout[(size_t)row * 64 + cf] = (__bf16)(rv * hid[(size_t)row * 64 + cf]);
          }
        } else {
          if (col < 64) {
            g += s * b0[cf];
            float cv = 1.f - 2.f / (1.f + __expf(2.f * g));
            float zv = zbuf[(size_t)row * 64 + cf];
            float hv = hid[(size_t)row * 64 + cf];
            outp[(size_t)row * 64 + cf] = (1.f - zv) * hv + zv * cv;
          }
        }
      }
    }
}

// ---------------------------------------------------------------------------
extern "C" void kernel_launch(void* const* d_in, const int* in_sizes, int n_in,
                              void* d_out, int out_size, void* d_ws, size_t ws_size,
                              hipStream_t stream) {
  (void)in_sizes; (void)n_in; (void)out_size;
  const float* x    = (const float*)d_in[0];
  const float* A1   = (const float*)d_in[1];
  const float* A2   = (const float*)d_in[2];
  const float* E1   = (const float*)d_in[3];
  const float* E2   = (const float*)d_in[4];
  const float* Wz   = (const float*)d_in[5];
  const float* bz   = (const float*)d_in[6];
  const float* Wr   = (const float*)d_in[7];
  const float* br   = (const float*)d_in[8];
  const float* Wc   = (const float*)d_in[9];
  const float* bc   = (const float*)d_in[10];
  const float* wpre = (const float*)d_in[11];
  const float* wadp = (const float*)d_in[12];
  float* out = (float*)d_out;

  char* ws = (char*)d_ws;
  const size_t NN2 = (size_t)NNODE * NNODE;  // 4,194,304 (= B*N*D too)
  const size_t NN2B = NN2 * 2;               // bytes per bf16 slice
  __bf16* ADJ  = (__bf16*)(ws);                 // [0,6) bf16 slices
  __bf16* ADJT = (__bf16*)(ws + 6 * NN2B);      // [6,12) w-scaled transposes
  __bf16* SC   = (__bf16*)(ws + 12 * NN2B);     // scores (4 slices), then:
  float*  M2p  = (float*)(ws + 12 * NN2B);      // f32 partials x2 = [12,16)
  __bf16* MM   = (__bf16*)(ws + 18 * NN2B);     // M1 @18, M2 @19
  __bf16* XT   = (__bf16*)(ws + 20 * NN2B);
  __bf16* xbf  = (__bf16*)(ws + 21 * NN2B);
  __bf16* rx   = (__bf16*)(ws + 22 * NN2B);
  __bf16* S1   = (__bf16*)(ws + 2 * NN2B);      // over ADJ[2] (dead post-sq)
  __bf16* S2   = (__bf16*)(ws + 3 * NN2B);      // over ADJ[3]
  float*  zbuf = (float*)(ws + 4 * NN2B);       // over ADJ[4..5]
  __bf16* E1p  = (__bf16*)(ws + 23 * NN2B);
  __bf16* E2p  = E1p + 4 * NNODE * 32;
  __bf16* Wzrt = E2p + 4 * NNODE * 32;
  __bf16* Wct  = Wzrt + 128 * 192;
  if (ws_size < 23 * NN2B + 2 * 4 * NNODE * 32 * 2 + 2 * 128 * 192 * 2) return;

  // --- adjacency construction (fused)
  prep_ew<<<224, 256, 0, stream>>>(E1, E2, Wz, Wr, Wc, wpre, wadp,
                                   E1p, E2p, Wzrt, Wct);
  score_gemm<<<dim3(16, 16, 4), 256, 0, stream>>>(E1p, E2p, SC);
  softmax_rows<<<2048, 256, 0, stream>>>(SC, ADJ + 2 * NN2);
  prep_adj<<<dim3(32, 32), 256, 0, stream>>>(A1, A2, ADJ, ADJT, MM, wpre, wadp);
  transpose_x<<<dim3(32, 32), 256, 0, stream>>>(x, XT, xbf);

  // --- M2 = sum_z w_z A_z^2 (fused accumulate; 512 blocks, XCD-chunked)
  gemm_sq<<<dim3(16, 16, 2), 256, 65536, stream>>>(ADJ, ADJT, M2p);
  combine_m2<<<4096, 256, 0, stream>>>(M2p, MM + NN2);

  // --- stage 1: S1 = M1 x, S2 = M2 x (fused transposed epilogue)
  gemm_hop1s<<<dim3(16, 16, 2), 256, 65536, stream>>>(XT, MM, S1, S2);
  gemm_lin<0><<<512, 256, 0, stream>>>(xbf, S1, S2, Wzrt, bz, br, wpre, wadp,
                                       x, zbuf, rx, nullptr);

  // --- stage 2: hops on r*x
  transpose_rx<<<dim3(32, 32), 256, 0, stream>>>(rx, XT);
  gemm_hop1s<<<dim3(16, 16, 2), 256, 65536, stream>>>(XT, MM, S1, S2);
  gemm_lin<1><<<512, 256, 0, stream>>>(rx, S1, S2, Wct, bc, nullptr, wpre, wadp,
                                       x, zbuf, nullptr, out);
}

// Round 11
// 270.306 us; speedup vs baseline: 1.0114x; 1.0114x over previous
//
#include <hip/hip_runtime.h>

#define NNODE 2048
#define NBATCH 32

typedef __attribute__((ext_vector_type(4))) float f32x4;
typedef __attribute__((ext_vector_type(8))) __bf16 bf16x8;
typedef __attribute__((ext_vector_type(4))) __bf16 bf16x4;

__device__ __forceinline__ void gload16(const void* g, void* lds) {
  __builtin_amdgcn_global_load_lds(
      (const __attribute__((address_space(1))) unsigned int*)g,
      (__attribute__((address_space(3))) unsigned int*)lds, 16, 0, 0);
}

// ---------------------------------------------------------------------------
// Merged: prep_e (blocks 0..127) + prep_w (blocks 128..223)
__global__ __launch_bounds__(256) void prep_ew(const float* __restrict__ E1,
                                               const float* __restrict__ E2,
                                               const float* __restrict__ Wz,
                                               const float* __restrict__ Wr,
                                               const float* __restrict__ Wc,
                                               const float* __restrict__ wpre,
                                               const float* __restrict__ wadp,
                                               __bf16* __restrict__ E1p,
                                               __bf16* __restrict__ E2p,
                                               __bf16* __restrict__ Wzrt,
                                               __bf16* __restrict__ Wct) {
  if (blockIdx.x < 128) {
    int idx = blockIdx.x * 256 + threadIdx.x;  // 0..32767
    int cq = idx & 3;
    int n = (idx >> 2) & 2047;
    int h = idx >> 13;
    const float4 q1 = *(const float4*)(E1 + (size_t)(n * 4 + h) * 16 + cq * 4);
    const float4 q2 = *(const float4*)(E2 + (size_t)(n * 4 + h) * 16 + cq * 4);
    size_t o = ((size_t)h * NNODE + n) * 32 + cq * 4;
    E1p[o + 0] = (__bf16)q1.x; E1p[o + 1] = (__bf16)q1.y;
    E1p[o + 2] = (__bf16)q1.z; E1p[o + 3] = (__bf16)q1.w;
    E2p[o + 0] = (__bf16)q2.x; E2p[o + 1] = (__bf16)q2.y;
    E2p[o + 2] = (__bf16)q2.z; E2p[o + 3] = (__bf16)q2.w;
    size_t oz = o + 16;
    E1p[oz + 0] = (__bf16)0.f; E1p[oz + 1] = (__bf16)0.f;
    E1p[oz + 2] = (__bf16)0.f; E1p[oz + 3] = (__bf16)0.f;
    E2p[oz + 0] = (__bf16)0.f; E2p[oz + 1] = (__bf16)0.f;
    E2p[oz + 2] = (__bf16)0.f; E2p[oz + 3] = (__bf16)0.f;
  } else {
    int idx = (blockIdx.x - 128) * 256 + threadIdx.x;  // 0 .. 128*192-1
    int rr = idx / 192, k = idx % 192;
    float s = 2.f * (*wpre) + (*wadp);
    float sc = (k < 64) ? s : 1.f;
    float vz = (rr < 64) ? Wz[(size_t)k * 64 + rr] : Wr[(size_t)k * 64 + rr - 64];
    Wzrt[idx] = (__bf16)(vz * sc);
    float vc = (rr < 64) ? Wc[(size_t)k * 64 + rr] * sc : 0.f;
    Wct[idx] = (__bf16)vc;
  }
}

// ---------------------------------------------------------------------------
// SC[h][w][v] = relu(E1p_h @ E2p_h^T)/4, bf16. Single K=32 MFMA step.
__global__ __launch_bounds__(256) void score_gemm(const __bf16* __restrict__ E1p,
                                                  const __bf16* __restrict__ E2p,
                                                  __bf16* __restrict__ SC) {
  __shared__ __bf16 As[128 * 32];
  __shared__ __bf16 Bs[128 * 32];
  const int tid = threadIdx.x;
  const int wave = tid >> 6, lane = tid & 63;
  const int wr = wave >> 1, wc = wave & 1;
  const int h = blockIdx.z;
  const int m0 = blockIdx.x * 128, n0 = blockIdx.y * 128;
  const __bf16* A = E1p + (size_t)h * NNODE * 32;
  const __bf16* Bt = E2p + (size_t)h * NNODE * 32;
  const int rowA = tid >> 2;
  const int colb = (tid & 3) * 16;
  gload16((const char*)(A + (size_t)(m0 + rowA) * 32) + colb, (char*)As + wave * 1024);
  gload16((const char*)(A + (size_t)(m0 + rowA + 64) * 32) + colb, (char*)As + 4096 + wave * 1024);
  gload16((const char*)(Bt + (size_t)(n0 + rowA) * 32) + colb, (char*)Bs + wave * 1024);
  gload16((const char*)(Bt + (size_t)(n0 + rowA + 64) * 32) + colb, (char*)Bs + 4096 + wave * 1024);
  __syncthreads();

  f32x4 acc[4][4] = {};
  bf16x8 af[4], bfr[4];
#pragma unroll
  for (int mi = 0; mi < 4; ++mi)
    af[mi] = *(const bf16x8*)((const char*)As +
             ((wr * 64 + mi * 16 + (lane & 15)) * 64 + (lane >> 4) * 16));
#pragma unroll
  for (int ni = 0; ni < 4; ++ni)
    bfr[ni] = *(const bf16x8*)((const char*)Bs +
             ((wc * 64 + ni * 16 + (lane & 15)) * 64 + (lane >> 4) * 16));
#pragma unroll
  for (int mi = 0; mi < 4; ++mi)
#pragma unroll
    for (int ni = 0; ni < 4; ++ni)
      acc[mi][ni] = __builtin_amdgcn_mfma_f32_16x16x32_bf16(af[mi], bfr[ni],
                                                            acc[mi][ni], 0, 0, 0);

  const int crow = (lane >> 4) * 4;
  const int ccol = lane & 15;
#pragma unroll
  for (int mi = 0; mi < 4; ++mi)
#pragma unroll
    for (int ni = 0; ni < 4; ++ni) {
      int r0 = m0 + wr * 64 + mi * 16 + crow;
      int cc = n0 + wc * 64 + ni * 16 + ccol;
#pragma unroll
      for (int r = 0; r < 4; ++r) {
        float val = fmaxf(acc[mi][ni][r], 0.f) * 0.25f;
        SC[((size_t)h * NNODE + r0 + r) * NNODE + cc] = (__bf16)val;
      }
    }
}

// ---------------------------------------------------------------------------
// Row softmax over v: one wave per row of SC [8192 x 2048] bf16 -> adjh bf16
__global__ __launch_bounds__(256) void softmax_rows(const __bf16* __restrict__ SC,
                                                    __bf16* __restrict__ adjh) {
  const int tid = threadIdx.x;
  const int wave = tid >> 6, lane = tid & 63;
  const size_t row = (size_t)blockIdx.x * 4 + wave;
  const __bf16* src = SC + row * NNODE;
  __bf16* dst = adjh + row * NNODE;
  float v[32];
  float mx = 0.f;
#pragma unroll
  for (int j = 0; j < 4; ++j) {
    bf16x8 q = *(const bf16x8*)(src + j * 512 + lane * 8);
#pragma unroll
    for (int i = 0; i < 8; ++i) {
      float f = (float)q[i];
      v[j * 8 + i] = f;
      mx = fmaxf(mx, f);
    }
  }
#pragma unroll
  for (int o = 32; o > 0; o >>= 1) mx = fmaxf(mx, __shfl_xor(mx, o));
  float s = 0.f;
#pragma unroll
  for (int i = 0; i < 32; ++i) {
    v[i] = __expf(v[i] - mx);
    s += v[i];
  }
#pragma unroll
  for (int o = 32; o > 0; o >>= 1) s += __shfl_xor(s, o);
  float inv = 1.f / s;
#pragma unroll
  for (int j = 0; j < 4; ++j) {
    bf16x8 q;
#pragma unroll
    for (int i = 0; i < 8; ++i) q[i] = (__bf16)(v[j * 8 + i] * inv);
    *(bf16x8*)(dst + j * 512 + lane * 8) = q;
  }
}

// ---------------------------------------------------------------------------
// Fused adjacency prep: ADJ bf16, w-scaled ADJT, M1 accum. (R8-verified)
__global__ __launch_bounds__(256) void prep_adj(const float* __restrict__ A1,
                                                const float* __restrict__ A2,
                                                __bf16* __restrict__ ADJ,
                                                __bf16* __restrict__ ADJT,
                                                __bf16* __restrict__ M1,
                                                const float* __restrict__ wpre,
                                                const float* __restrict__ wadp) {
  const int r0 = blockIdx.x * 64, c0 = blockIdx.y * 64;
  const int tid = threadIdx.x;
  const size_t NN2 = (size_t)NNODE * NNODE;
  const float wp = *wpre, wa = *wadp * 0.25f;
  __shared__ float t[64][65];
  const int vr = tid >> 2, cg = (tid & 3) * 16;
  float m1acc[16] = {};

  for (int z = 0; z < 6; ++z) {
    const float wz = (z < 2) ? wp : wa;
    float vv[16];
    if (z < 2) {
      const float* src = (z == 0 ? A1 : A2) + (size_t)(r0 + vr) * NNODE + c0 + cg;
#pragma unroll
      for (int j = 0; j < 4; ++j) {
        float4 q = ((const float4*)src)[j];
        vv[j * 4 + 0] = q.x; vv[j * 4 + 1] = q.y;
        vv[j * 4 + 2] = q.z; vv[j * 4 + 3] = q.w;
      }
      __bf16* q = ADJ + (size_t)z * NN2 + (size_t)(r0 + vr) * NNODE + c0 + cg;
      bf16x8 o0, o1;
#pragma unroll
      for (int i = 0; i < 8; ++i) { o0[i] = (__bf16)vv[i]; o1[i] = (__bf16)vv[8 + i]; }
      ((bf16x8*)q)[0] = o0;
      ((bf16x8*)q)[1] = o1;
    } else {
      const __bf16* p = ADJ + (size_t)z * NN2 + (size_t)(r0 + vr) * NNODE + c0 + cg;
      bf16x8 q0 = ((const bf16x8*)p)[0];
      bf16x8 q1 = ((const bf16x8*)p)[1];
#pragma unroll
      for (int i = 0; i < 8; ++i) { vv[i] = (float)q0[i]; vv[8 + i] = (float)q1[i]; }
    }
#pragma unroll
    for (int i = 0; i < 16; ++i) {
      m1acc[i] += wz * vv[i];
      t[vr][cg + i] = vv[i];
    }
    __syncthreads();
#pragma unroll
    for (int jr = 0; jr < 16; ++jr) {
      int c = jr * 4 + (tid >> 6);
      int v = tid & 63;
      ADJT[(size_t)z * NN2 + (size_t)(c0 + c) * NNODE + r0 + v] = (__bf16)(wz * t[v][c]);
    }
    __syncthreads();
  }
  __bf16* q = M1 + (size_t)(r0 + vr) * NNODE + c0 + cg;
  bf16x8 o0, o1;
#pragma unroll
  for (int i = 0; i < 8; ++i) { o0[i] = (__bf16)m1acc[i]; o1[i] = (__bf16)m1acc[8 + i]; }
  ((bf16x8*)q)[0] = o0;
  ((bf16x8*)q)[1] = o1;
}

// ---------------------------------------------------------------------------
// x f32 [B,N,64] -> XT bf16 [B*64, N] and xbf bf16 [B*N,64]
__global__ __launch_bounds__(256) void transpose_x(const float* __restrict__ x,
                                                   __bf16* __restrict__ XT,
                                                   __bf16* __restrict__ xbf) {
  const int b = blockIdx.y, v0 = blockIdx.x * 64;
  const int tid = threadIdx.x;
  __shared__ float t[64][65];
  const int vr = tid >> 2, c0 = (tid & 3) * 16;
  const float* src = x + ((size_t)b * NNODE + v0 + vr) * 64 + c0;
  __bf16* xb = xbf + ((size_t)b * NNODE + v0 + vr) * 64 + c0;
#pragma unroll
  for (int j = 0; j < 4; ++j) {
    float4 q = ((const float4*)src)[j];
    t[vr][c0 + j * 4 + 0] = q.x;
    t[vr][c0 + j * 4 + 1] = q.y;
    t[vr][c0 + j * 4 + 2] = q.z;
    t[vr][c0 + j * 4 + 3] = q.w;
    xb[j * 4 + 0] = (__bf16)q.x;
    xb[j * 4 + 1] = (__bf16)q.y;
    xb[j * 4 + 2] = (__bf16)q.z;
    xb[j * 4 + 3] = (__bf16)q.w;
  }
  __syncthreads();
#pragma unroll
  for (int jr = 0; jr < 16; ++jr) {
    int c = jr * 4 + (tid >> 6);
    int v = tid & 63;
    XT[((size_t)b * 64 + c) * NNODE + v0 + v] = (__bf16)t[v][c];
  }
}

// rx bf16 [B*N,64] -> XT bf16 [B*64, N]
__global__ __launch_bounds__(256) void transpose_rx(const __bf16* __restrict__ rx,
                                                    __bf16* __restrict__ XT) {
  const int b = blockIdx.y, v0 = blockIdx.x * 64;
  const int tid = threadIdx.x;
  __shared__ float t[64][65];
  const int vr = tid >> 2, c0 = (tid & 3) * 16;
  const __bf16* src = rx + ((size_t)b * NNODE + v0 + vr) * 64 + c0;
  bf16x8 q0 = ((const bf16x8*)src)[0];
  bf16x8 q1 = ((const bf16x8*)src)[1];
#pragma unroll
  for (int i = 0; i < 8; ++i) {
    t[vr][c0 + i] = (float)q0[i];
    t[vr][c0 + 8 + i] = (float)q1[i];
  }
  __syncthreads();
#pragma unroll
  for (int jr = 0; jr < 16; ++jr) {
    int c = jr * 4 + (tid >> 6);
    int v = tid & 63;
    XT[((size_t)b * 64 + c) * NNODE + v0 + v] = (__bf16)t[v][c];
  }
}

// ---------------------------------------------------------------------------
// Shared GEMM machinery: 128x128, BK=64, 4 waves, 2 blocks/CU, counted
// vmcnt(8), verified 3-bit XOR swizzle. R11: register-double-buffered
// software pipeline — ds_read frags(t+1) issued BEFORE MFMA(t) so LDS reads
// overlap MFMA within each wave. Statically-named reg sets (no dyn indexing).
#define VMCNT0() asm volatile("s_waitcnt vmcnt(0)" ::: "memory")
#define VMCNT8() asm volatile("s_waitcnt vmcnt(8)" ::: "memory")
#define LGKMCNT0() asm volatile("s_waitcnt lgkmcnt(0)" ::: "memory")
#define BARRIER() asm volatile("s_barrier" ::: "memory")

#define READFRAGS(d, AF, BF)                                                  \
  do {                                                                        \
    _Pragma("unroll")                                                         \
    for (int mi = 0; mi < 4; ++mi) {                                          \
      AF[mi][0] = *(const bf16x8*)(AREG(d) + aoff[mi][0]);                    \
      AF[mi][1] = *(const bf16x8*)(AREG(d) + aoff[mi][1]);                    \
    }                                                                         \
    _Pragma("unroll")                                                         \
    for (int j = 0; j < 4; ++j) {                                             \
      BF[j][0] = *(const bf16x8*)(BREG(d) + boff[j][0]);                      \
      BF[j][1] = *(const bf16x8*)(BREG(d) + boff[j][1]);                      \
    }                                                                         \
  } while (0)

#define MFMA16(AF, BF)                                                        \
  do {                                                                        \
    __builtin_amdgcn_s_setprio(1);                                            \
    _Pragma("unroll")                                                         \
    for (int mi = 0; mi < 4; ++mi)                                            \
      _Pragma("unroll")                                                       \
      for (int j = 0; j < 4; ++j)                                             \
        _Pragma("unroll")                                                     \
        for (int ks = 0; ks < 2; ++ks)                                        \
          acc[mi][j] = __builtin_amdgcn_mfma_f32_16x16x32_bf16(               \
              AF[mi][ks], BF[j][ks], acc[mi][j], 0, 0, 0);                    \
    __builtin_amdgcn_s_setprio(0);                                            \
  } while (0)

// Fused-squares: M2part[zh] = sum_{z in half} ADJ_z @ ADJT_z^T (ADJT w-scaled),
// f32 partials. 96 K-tiles/block. XCD-chunked block swizzle.
__global__ __launch_bounds__(256, 2) void gemm_sq(const __bf16* __restrict__ ADJ,
                                                  const __bf16* __restrict__ ADJT,
                                                  float* __restrict__ M2part) {
  extern __shared__ char smem[];  // 65536 B
  const int tid = threadIdx.x;
  const int w = tid >> 6, l = tid & 63;
  const int wr = w >> 1, wc = w & 1;
  const size_t NN2 = (size_t)NNODE * NNODE;
  const size_t NN2B2 = NN2 * 2;
  int lin = blockIdx.x + 16 * blockIdx.y + 256 * blockIdx.z;
  int nlin = (lin & 7) * 64 + (lin >> 3);
  const int m0 = (nlin & 15) * 128, n0 = ((nlin >> 4) & 15) * 128;
  const int zh = nlin >> 8;
  const int zb = zh * 3;
  float* Cp = M2part + (size_t)zh * NN2;
  const int NTT = 96;  // 3 z * 32 K-tiles

#define AREG(d) (smem + (d) * 16384)
#define BREG(d) (smem + 32768 + (d) * 16384)

  int aoff[4][2], boff[4][2];
#pragma unroll
  for (int mi = 0; mi < 4; ++mi)
#pragma unroll
    for (int ks = 0; ks < 2; ++ks) {
      int rh = mi * 32 + wr * 16 + (l & 15);
      int lo = rh * 128 + ks * 64 + ((l >> 4) * 16);
      aoff[mi][ks] = lo ^ ((rh & 7) << 4);
    }
#pragma unroll
  for (int j = 0; j < 4; ++j)
#pragma unroll
    for (int ks = 0; ks < 2; ++ks) {
      int rh = j * 32 + wc * 16 + (l & 15);
      int lo = rh * 128 + ks * 64 + ((l >> 4) * 16);
      boff[j][ks] = lo ^ ((rh & 7) << 4);
    }

  const int sg_row = w * 8 + (l >> 3);
  const int sg_col = (((l & 7) ^ ((l >> 3) & 7)) << 4);
  unsigned aLoff[4], bLoff[4];
#pragma unroll
  for (int p = 0; p < 4; ++p) {
    aLoff[p] = (unsigned)((m0 + p * 32 + sg_row) * 4096 + sg_col);
    bLoff[p] = (unsigned)((n0 + p * 32 + sg_row) * 4096 + sg_col);
  }

#define STAGEOFF(toff, region)                                                \
  do {                                                                        \
    _Pragma("unroll")                                                         \
    for (int p = 0; p < 4; ++p)                                               \
      gload16((const char*)ADJ + (toff) + aLoff[p],                           \
              (region) + p * 4096 + w * 1024);                                \
  } while (0)
#define STAGEOFFB(toff, region)                                               \
  do {                                                                        \
    _Pragma("unroll")                                                         \
    for (int p = 0; p < 4; ++p)                                               \
      gload16((const char*)ADJT + (toff) + bLoff[p],                          \
              (region) + p * 4096 + w * 1024);                                \
  } while (0)

  f32x4 acc[4][4] = {};
  bf16x8 afA[4][2], bfA[4][2], afB[4][2], bfB[4][2];

  // prologue: tiles 0,1 staged; frags(0) read into A-set
  size_t tOff = (size_t)zb * NN2B2;
  STAGEOFF(tOff, AREG(0));
  STAGEOFFB(tOff, BREG(0));
  STAGEOFF(tOff + 128, AREG(1));
  STAGEOFFB(tOff + 128, BREG(1));
  tOff += 256;
  VMCNT8();   // tile0 landed
  BARRIER();
  READFRAGS(0, afA, bfA);
  LGKMCNT0();
  BARRIER();  // all waves done reading buf0 -> loop may overwrite it

  // main loop: double-body, tiles t (A-set) and t+1 (B-set); t <= NTT-4
  for (int t = 0; t <= NTT - 4; t += 2) {
    // --- sub-iter t (even): stage t+2 -> buf0, read frags(t+1), MFMA(t)
    STAGEOFF(tOff, AREG(0));
    STAGEOFFB(tOff, BREG(0));
    tOff += (((t + 2) & 31) == 31) ? (NN2B2 - (size_t)31 * 128) : (size_t)128;
    VMCNT8();   // t+1 landed; t+2 in flight
    BARRIER();
    READFRAGS(1, afB, bfB);   // frags(t+1), overlaps MFMA below
    MFMA16(afA, bfA);         // compute tile t
    LGKMCNT0();
    BARRIER();                // all waves done reading buf1
    // --- sub-iter t+1 (odd): stage t+3 -> buf1, read frags(t+2), MFMA(t+1)
    STAGEOFF(tOff, AREG(1));
    STAGEOFFB(tOff, BREG(1));
    tOff += (((t + 3) & 31) == 31) ? (NN2B2 - (size_t)31 * 128) : (size_t)128;
    VMCNT8();   // t+2 landed; t+3 in flight
    BARRIER();
    READFRAGS(0, afA, bfA);   // frags(t+2)
    MFMA16(afB, bfB);         // compute tile t+1
    LGKMCNT0();
    BARRIER();
  }
  // tail: afA holds frags(NTT-2); buf1 holds tile NTT-1 in flight
  VMCNT0();
  BARRIER();
  READFRAGS(1, afB, bfB);     // frags(NTT-1)
  MFMA16(afA, bfA);           // compute NTT-2
  LGKMCNT0();
  MFMA16(afB, bfB);           // compute NTT-1

  const int crow = (l >> 4) * 4;
  const int ccol = l & 15;
#pragma unroll
  for (int mi = 0; mi < 4; ++mi)
#pragma unroll
    for (int j = 0; j < 4; ++j) {
      int r0 = m0 + mi * 32 + wr * 16 + crow;
      int cc = n0 + j * 32 + wc * 16 + ccol;
#pragma unroll
      for (int r = 0; r < 4; ++r)
        Cp[(size_t)(r0 + r) * NNODE + cc] = acc[mi][j][r];
    }
#undef STAGEOFF
#undef STAGEOFFB
#undef AREG
#undef BREG
}

// ---------------------------------------------------------------------------
// Stage GEMM with fused transposed epilogue (R9-verified epilogue), R11
// register-pipelined K-loop.
__global__ __launch_bounds__(256, 2) void gemm_hop1s(const __bf16* __restrict__ XT,
                                                     const __bf16* __restrict__ MMb,
                                                     __bf16* __restrict__ S1,
                                                     __bf16* __restrict__ S2) {
  extern __shared__ char smem[];  // 65536 B
  const int tid = threadIdx.x;
  const int w = tid >> 6, l = tid & 63;
  const int wr = w >> 1, wc = w & 1;
  const size_t NN2 = (size_t)NNODE * NNODE;
  int lin = blockIdx.x + 16 * blockIdx.y + 256 * blockIdx.z;
  int nlin = (lin & 7) * 64 + (lin >> 3);
  const int m0 = (nlin & 15) * 128, n0 = ((nlin >> 4) & 15) * 128;
  const int z = nlin >> 8;
  const char* Abase = (const char*)XT;
  const char* Bbase = (const char*)(MMb + (size_t)z * NN2);
  const int NT = NNODE / 64;  // 32

#define AREG(d) (smem + (d) * 16384)
#define BREG(d) (smem + 32768 + (d) * 16384)

  int aoff[4][2], boff[4][2];
#pragma unroll
  for (int mi = 0; mi < 4; ++mi)
#pragma unroll
    for (int ks = 0; ks < 2; ++ks) {
      int rh = mi * 32 + wr * 16 + (l & 15);
      int lo = rh * 128 + ks * 64 + ((l >> 4) * 16);
      aoff[mi][ks] = lo ^ ((rh & 7) << 4);
    }
#pragma unroll
  for (int j = 0; j < 4; ++j)
#pragma unroll
    for (int ks = 0; ks < 2; ++ks) {
      int rh = j * 32 + wc * 16 + (l & 15);
      int lo = rh * 128 + ks * 64 + ((l >> 4) * 16);
      boff[j][ks] = lo ^ ((rh & 7) << 4);
    }

  const int sg_row = w * 8 + (l >> 3);
  const int sg_col = (((l & 7) ^ ((l >> 3) & 7)) << 4);
  unsigned aLoff[4], bLoff[4];
#pragma unroll
  for (int p = 0; p < 4; ++p) {
    aLoff[p] = (unsigned)((m0 + p * 32 + sg_row) * 4096 + sg_col);
    bLoff[p] = (unsigned)((n0 + p * 32 + sg_row) * 4096 + sg_col);
  }

#define STAGEA(koff, region)                                                  \
  do {                                                                        \
    _Pragma("unroll")                                                         \
    for (int p = 0; p < 4; ++p)                                               \
      gload16(Abase + (koff) + aLoff[p], (region) + p * 4096 + w * 1024);     \
  } while (0)
#define STAGEB(koff, region)                                                  \
  do {                                                                        \
    _Pragma("unroll")                                                         \
    for (int p = 0; p < 4; ++p)                                               \
      gload16(Bbase + (koff) + bLoff[p], (region) + p * 4096 + w * 1024);     \
  } while (0)

  f32x4 acc[4][4] = {};
  bf16x8 afA[4][2], bfA[4][2], afB[4][2], bfB[4][2];

  size_t kOff = 0;
  STAGEA(kOff, AREG(0));
  STAGEB(kOff, BREG(0));
  STAGEA(kOff + 128, AREG(1));
  STAGEB(kOff + 128, BREG(1));
  kOff += 256;
  VMCNT8();
  BARRIER();
  READFRAGS(0, afA, bfA);
  LGKMCNT0();
  BARRIER();

  for (int t = 0; t <= NT - 4; t += 2) {
    STAGEA(kOff, AREG(0));
    STAGEB(kOff, BREG(0));
    kOff += 128;
    VMCNT8();
    BARRIER();
    READFRAGS(1, afB, bfB);
    MFMA16(afA, bfA);
    LGKMCNT0();
    BARRIER();
    STAGEA(kOff, AREG(1));
    STAGEB(kOff, BREG(1));
    kOff += 128;
    VMCNT8();
    BARRIER();
    READFRAGS(0, afA, bfA);
    MFMA16(afB, bfB);
    LGKMCNT0();
    BARRIER();
  }
  VMCNT0();
  BARRIER();
  READFRAGS(1, afB, bfB);
  MFMA16(afA, bfA);
  LGKMCNT0();
  MFMA16(afB, bfB);

  // ---- epilogue (R9-verified): LDS transpose T[n][m] with slot-XOR swizzle,
  // coalesced write S_z[(b, n0+n)*64 + c].
  {
    __syncthreads();  // all LDS reads done before reusing smem as T
    const int crow = (l >> 4) * 4;
    const int ccol = l & 15;
    char* T = smem;  // 128 x 256 B = 32 KiB
#pragma unroll
    for (int mi = 0; mi < 4; ++mi)
#pragma unroll
      for (int j = 0; j < 4; ++j) {
        int ml = mi * 32 + wr * 16 + crow;
        int nl = j * 32 + wc * 16 + ccol;
        bf16x4 v;
#pragma unroll
        for (int r = 0; r < 4; ++r) v[r] = (__bf16)acc[mi][j][r];
        *(bf16x4*)(T + nl * 256 + ((ml * 2) ^ ((nl & 7) << 4))) = v;
      }
    __syncthreads();
    __bf16* dst = z ? S2 : S1;
    const int bA = m0 >> 6;
#pragma unroll
    for (int it = 0; it < 4; ++it) {
      int nl = (tid >> 3) + it * 32;
      int seg = tid & 7;
      int xorv = (nl & 7) << 4;
      const char* src = T + nl * 256;
      bf16x8 v0 = *(const bf16x8*)(src + ((seg * 32) ^ xorv));
      bf16x8 v1 = *(const bf16x8*)(src + ((seg * 32 + 16) ^ xorv));
      int b = bA + (seg >> 2);
      size_t o = ((size_t)b * NNODE + n0 + nl) * 64 + (seg & 3) * 16;
      *(bf16x8*)(dst + o) = v0;
      *(bf16x8*)(dst + o + 8) = v1;
    }
  }
#undef STAGEA
#undef STAGEB
#undef AREG
#undef BREG
}

// ---------------------------------------------------------------------------
// M2[i] = (bf16)(M2a[i] + M2b[i])
__global__ __launch_bounds__(256) void combine_m2(const float* __restrict__ M2p,
                                                  __bf16* __restrict__ M2) {
  const size_t NN2 = (size_t)NNODE * NNODE;
  size_t i = ((size_t)blockIdx.x * 256 + threadIdx.x) * 4;
  float4 a = *(const float4*)(M2p + i);
  float4 b = *(const float4*)(M2p + NN2 + i);
  M2[i + 0] = (__bf16)(a.x + b.x);
  M2[i + 1] = (__bf16)(a.y + b.y);
  M2[i + 2] = (__bf16)(a.z + b.z);
  M2[i + 3] = (__bf16)(a.w + b.w);
}

// ---------------------------------------------------------------------------
// Gate linear GEMM: [65536 x 192] @ Wt^T, K=192, N=128, fused epilogues.
template <int MODE>
__global__ __launch_bounds__(256) void gemm_lin(const __bf16* __restrict__ Xp,
                                                const __bf16* __restrict__ S1,
                                                const __bf16* __restrict__ S2,
                                                const __bf16* __restrict__ Wt,
                                                const float* __restrict__ b0,
                                                const float* __restrict__ b1,
                                                const float* __restrict__ wpre,
                                                const float* __restrict__ wadp,
                                                const float* __restrict__ hid,
                                                float* __restrict__ zbuf,
                                                __bf16* __restrict__ rxout,
                                                float* __restrict__ outp) {
  __shared__ __bf16 As[128 * 32];
  __shared__ __bf16 Bs[128 * 32];
  const int tid = threadIdx.x;
  const int wave = tid >> 6, lane = tid & 63;
  const int wr = wave >> 1, wc = wave & 1;
  const int m0 = blockIdx.x * 128;
  const int rowA = tid >> 2;
  const int colb = (tid & 3) * 16;
  const __bf16* srcs[3] = {Xp, S1, S2};
  char* asD0 = (char*)As + wave * 1024;
  char* asD1 = (char*)As + 4096 + wave * 1024;
  char* bsD0 = (char*)Bs + wave * 1024;
  char* bsD1 = (char*)Bs + 4096 + wave * 1024;

  f32x4 acc[4][4] = {};

#pragma unroll
  for (int kt = 0; kt < 6; ++kt) {
    const __bf16* Ab = srcs[kt >> 1];
    const char* aS0 = (const char*)(Ab + (size_t)(m0 + rowA) * 64) + (kt & 1) * 64 + colb;
    const char* aS1 = (const char*)(Ab + (size_t)(m0 + rowA + 64) * 64) + (kt & 1) * 64 + colb;
    const char* bS0 = (const char*)(Wt + (size_t)rowA * 192) + kt * 64 + colb;
    const char* bS1 = (const char*)(Wt + (size_t)(rowA + 64) * 192) + kt * 64 + colb;
    gload16(aS0, asD0);
    gload16(aS1, asD1);
    gload16(bS0, bsD0);
    gload16(bS1, bsD1);
    __syncthreads();
    bf16x8 af[4], bfr[4];
#pragma unroll
    for (int mi = 0; mi < 4; ++mi)
      af[mi] = *(const bf16x8*)((const char*)As +
               ((wr * 64 + mi * 16 + (lane & 15)) * 64 + (lane >> 4) * 16));
#pragma unroll
    for (int ni = 0; ni < 4; ++ni)
      bfr[ni] = *(const bf16x8*)((const char*)Bs +
               ((wc * 64 + ni * 16 + (lane & 15)) * 64 + (lane >> 4) * 16));
#pragma unroll
    for (int mi = 0; mi < 4; ++mi)
#pragma unroll
      for (int ni = 0; ni < 4; ++ni)
        acc[mi][ni] = __builtin_amdgcn_mfma_f32_16x16x32_bf16(af[mi], bfr[ni],
                                                              acc[mi][ni], 0, 0, 0);
    __syncthreads();
  }

  const float wp = *wpre, wa = *wadp;
  const float s = 2.f * wp + wa;
  const int crow = (lane >> 4) * 4;
  const int ccol = lane & 15;
#pragma unroll
  for (int mi = 0; mi < 4; ++mi)
#pragma unroll
    for (int ni = 0; ni < 4; ++ni) {
      int r0 = m0 + wr * 64 + mi * 16 + crow;
      int col = wc * 64 + ni * 16 + ccol;
      int cf = col & 63;
#pragma unroll
      for (int r = 0; r < 4; ++r) {
        int row = r0 + r;
        float g = acc[mi][ni][r];
        if (MODE == 0) {
          if (col < 64) {
            g += s * b0[cf];
            zbuf[(size_t)row * 64 + cf] = 1.f / (1.f + __expf(-g));
          } else {
            g += s * b1[cf];
            float rv = 1.f / (1.f + __expf(-g));
            rxout[(size_t)row * 64 + cf] = (__bf16)(rv * hid[(size_t)row * 64 + cf]);
          }
        } else {
          if (col < 64) {
            g += s * b0[cf];
            float cv = 1.f - 2.f / (1.f + __expf(2.f * g));
            float zv = zbuf[(size_t)row * 64 + cf];
            float hv = hid[(size_t)row * 64 + cf];
            outp[(size_t)row * 64 + cf] = (1.f - zv) * hv + zv * cv;
          }
        }
      }
    }
}

// ---------------------------------------------------------------------------
extern "C" void kernel_launch(void* const* d_in, const int* in_sizes, int n_in,
                              void* d_out, int out_size, void* d_ws, size_t ws_size,
                              hipStream_t stream) {
  (void)in_sizes; (void)n_in; (void)out_size;
  const float* x    = (const float*)d_in[0];
  const float* A1   = (const float*)d_in[1];
  const float* A2   = (const float*)d_in[2];
  const float* E1   = (const float*)d_in[3];
  const float* E2   = (const float*)d_in[4];
  const float* Wz   = (const float*)d_in[5];
  const float* bz   = (const float*)d_in[6];
  const float* Wr   = (const float*)d_in[7];
  const float* br   = (const float*)d_in[8];
  const float* Wc   = (const float*)d_in[9];
  const float* bc   = (const float*)d_in[10];
  const float* wpre = (const float*)d_in[11];
  const float* wadp = (const float*)d_in[12];
  float* out = (float*)d_out;

  char* ws = (char*)d_ws;
  const size_t NN2 = (size_t)NNODE * NNODE;  // 4,194,304 (= B*N*D too)
  const size_t NN2B = NN2 * 2;               // bytes per bf16 slice
  __bf16* ADJ  = (__bf16*)(ws);                 // [0,6) bf16 slices
  __bf16* ADJT = (__bf16*)(ws + 6 * NN2B);      // [6,12) w-scaled transposes
  __bf16* SC   = (__bf16*)(ws + 12 * NN2B);     // scores (4 slices), then:
  float*  M2p  = (float*)(ws + 12 * NN2B);      // f32 partials x2 = [12,16)
  __bf16* MM   = (__bf16*)(ws + 18 * NN2B);     // M1 @18, M2 @19
  __bf16* XT   = (__bf16*)(ws + 20 * NN2B);
  __bf16* xbf  = (__bf16*)(ws + 21 * NN2B);
  __bf16* rx   = (__bf16*)(ws + 22 * NN2B);
  __bf16* S1   = (__bf16*)(ws + 2 * NN2B);      // over ADJ[2] (dead post-sq)
  __bf16* S2   = (__bf16*)(ws + 3 * NN2B);      // over ADJ[3]
  float*  zbuf = (float*)(ws + 4 * NN2B);       // over ADJ[4..5]
  __bf16* E1p  = (__bf16*)(ws + 23 * NN2B);
  __bf16* E2p  = E1p + 4 * NNODE * 32;
  __bf16* Wzrt = E2p + 4 * NNODE * 32;
  __bf16* Wct  = Wzrt + 128 * 192;
  if (ws_size < 23 * NN2B + 2 * 4 * NNODE * 32 * 2 + 2 * 128 * 192 * 2) return;

  // --- adjacency construction (fused)
  prep_ew<<<224, 256, 0, stream>>>(E1, E2, Wz, Wr, Wc, wpre, wadp,
                                   E1p, E2p, Wzrt, Wct);
  score_gemm<<<dim3(16, 16, 4), 256, 0, stream>>>(E1p, E2p, SC);
  softmax_rows<<<2048, 256, 0, stream>>>(SC, ADJ + 2 * NN2);
  prep_adj<<<dim3(32, 32), 256, 0, stream>>>(A1, A2, ADJ, ADJT, MM, wpre, wadp);
  transpose_x<<<dim3(32, 32), 256, 0, stream>>>(x, XT, xbf);

  // --- M2 = sum_z w_z A_z^2 (fused accumulate; 512 blocks, XCD-chunked)
  gemm_sq<<<dim3(16, 16, 2), 256, 65536, stream>>>(ADJ, ADJT, M2p);
  combine_m2<<<4096, 256, 0, stream>>>(M2p, MM + NN2);

  // --- stage 1: S1 = M1 x, S2 = M2 x (fused transposed epilogue)
  gemm_hop1s<<<dim3(16, 16, 2), 256, 65536, stream>>>(XT, MM, S1, S2);
  gemm_lin<0><<<512, 256, 0, stream>>>(xbf, S1, S2, Wzrt, bz, br, wpre, wadp,
                                       x, zbuf, rx, nullptr);

  // --- stage 2: hops on r*x
  transpose_rx<<<dim3(32, 32), 256, 0, stream>>>(rx, XT);
  gemm_hop1s<<<dim3(16, 16, 2), 256, 65536, stream>>>(XT, MM, S1, S2);
  gemm_lin<1><<<512, 256, 0, stream>>>(rx, S1, S2, Wct, bc, nullptr, wpre, wadp,
                                       x, zbuf, nullptr, out);
}

// Round 12
// 254.479 us; speedup vs baseline: 1.0743x; 1.0622x over previous
//
#include <hip/hip_runtime.h>

#define NNODE 2048
#define NBATCH 32

typedef __attribute__((ext_vector_type(4))) float f32x4;
typedef __attribute__((ext_vector_type(8))) __bf16 bf16x8;
typedef __attribute__((ext_vector_type(4))) __bf16 bf16x4;

__device__ __forceinline__ void gload16(const void* g, void* lds) {
  __builtin_amdgcn_global_load_lds(
      (const __attribute__((address_space(1))) unsigned int*)g,
      (__attribute__((address_space(3))) unsigned int*)lds, 16, 0, 0);
}

// ---------------------------------------------------------------------------
// Merged: prep_e (blocks 0..127) + prep_w (blocks 128..223)
__global__ __launch_bounds__(256) void prep_ew(const float* __restrict__ E1,
                                               const float* __restrict__ E2,
                                               const float* __restrict__ Wz,
                                               const float* __restrict__ Wr,
                                               const float* __restrict__ Wc,
                                               const float* __restrict__ wpre,
                                               const float* __restrict__ wadp,
                                               __bf16* __restrict__ E1p,
                                               __bf16* __restrict__ E2p,
                                               __bf16* __restrict__ Wzrt,
                                               __bf16* __restrict__ Wct) {
  if (blockIdx.x < 128) {
    int idx = blockIdx.x * 256 + threadIdx.x;  // 0..32767
    int cq = idx & 3;
    int n = (idx >> 2) & 2047;
    int h = idx >> 13;
    const float4 q1 = *(const float4*)(E1 + (size_t)(n * 4 + h) * 16 + cq * 4);
    const float4 q2 = *(const float4*)(E2 + (size_t)(n * 4 + h) * 16 + cq * 4);
    size_t o = ((size_t)h * NNODE + n) * 32 + cq * 4;
    E1p[o + 0] = (__bf16)q1.x; E1p[o + 1] = (__bf16)q1.y;
    E1p[o + 2] = (__bf16)q1.z; E1p[o + 3] = (__bf16)q1.w;
    E2p[o + 0] = (__bf16)q2.x; E2p[o + 1] = (__bf16)q2.y;
    E2p[o + 2] = (__bf16)q2.z; E2p[o + 3] = (__bf16)q2.w;
    size_t oz = o + 16;
    E1p[oz + 0] = (__bf16)0.f; E1p[oz + 1] = (__bf16)0.f;
    E1p[oz + 2] = (__bf16)0.f; E1p[oz + 3] = (__bf16)0.f;
    E2p[oz + 0] = (__bf16)0.f; E2p[oz + 1] = (__bf16)0.f;
    E2p[oz + 2] = (__bf16)0.f; E2p[oz + 3] = (__bf16)0.f;
  } else {
    int idx = (blockIdx.x - 128) * 256 + threadIdx.x;  // 0 .. 128*192-1
    int rr = idx / 192, k = idx % 192;
    float s = 2.f * (*wpre) + (*wadp);
    float sc = (k < 64) ? s : 1.f;
    float vz = (rr < 64) ? Wz[(size_t)k * 64 + rr] : Wr[(size_t)k * 64 + rr - 64];
    Wzrt[idx] = (__bf16)(vz * sc);
    float vc = (rr < 64) ? Wc[(size_t)k * 64 + rr] * sc : 0.f;
    Wct[idx] = (__bf16)vc;
  }
}

// ---------------------------------------------------------------------------
// SC[h][w][v] = relu(E1p_h @ E2p_h^T)/4, bf16. Single K=32 MFMA step.
__global__ __launch_bounds__(256) void score_gemm(const __bf16* __restrict__ E1p,
                                                  const __bf16* __restrict__ E2p,
                                                  __bf16* __restrict__ SC) {
  __shared__ __bf16 As[128 * 32];
  __shared__ __bf16 Bs[128 * 32];
  const int tid = threadIdx.x;
  const int wave = tid >> 6, lane = tid & 63;
  const int wr = wave >> 1, wc = wave & 1;
  const int h = blockIdx.z;
  const int m0 = blockIdx.x * 128, n0 = blockIdx.y * 128;
  const __bf16* A = E1p + (size_t)h * NNODE * 32;
  const __bf16* Bt = E2p + (size_t)h * NNODE * 32;
  const int rowA = tid >> 2;
  const int colb = (tid & 3) * 16;
  gload16((const char*)(A + (size_t)(m0 + rowA) * 32) + colb, (char*)As + wave * 1024);
  gload16((const char*)(A + (size_t)(m0 + rowA + 64) * 32) + colb, (char*)As + 4096 + wave * 1024);
  gload16((const char*)(Bt + (size_t)(n0 + rowA) * 32) + colb, (char*)Bs + wave * 1024);
  gload16((const char*)(Bt + (size_t)(n0 + rowA + 64) * 32) + colb, (char*)Bs + 4096 + wave * 1024);
  __syncthreads();

  f32x4 acc[4][4] = {};
  bf16x8 af[4], bfr[4];
#pragma unroll
  for (int mi = 0; mi < 4; ++mi)
    af[mi] = *(const bf16x8*)((const char*)As +
             ((wr * 64 + mi * 16 + (lane & 15)) * 64 + (lane >> 4) * 16));
#pragma unroll
  for (int ni = 0; ni < 4; ++ni)
    bfr[ni] = *(const bf16x8*)((const char*)Bs +
             ((wc * 64 + ni * 16 + (lane & 15)) * 64 + (lane >> 4) * 16));
#pragma unroll
  for (int mi = 0; mi < 4; ++mi)
#pragma unroll
    for (int ni = 0; ni < 4; ++ni)
      acc[mi][ni] = __builtin_amdgcn_mfma_f32_16x16x32_bf16(af[mi], bfr[ni],
                                                            acc[mi][ni], 0, 0, 0);

  const int crow = (lane >> 4) * 4;
  const int ccol = lane & 15;
#pragma unroll
  for (int mi = 0; mi < 4; ++mi)
#pragma unroll
    for (int ni = 0; ni < 4; ++ni) {
      int r0 = m0 + wr * 64 + mi * 16 + crow;
      int cc = n0 + wc * 64 + ni * 16 + ccol;
#pragma unroll
      for (int r = 0; r < 4; ++r) {
        float val = fmaxf(acc[mi][ni][r], 0.f) * 0.25f;
        SC[((size_t)h * NNODE + r0 + r) * NNODE + cc] = (__bf16)val;
      }
    }
}

// ---------------------------------------------------------------------------
// Merged: blocks 0..2047 -> row softmax (SC -> adjh); blocks 2048..3071 ->
// transpose_x (x f32 [B,N,64] -> XT bf16 [B*64,N] and xbf bf16 [B*N,64]).
__global__ __launch_bounds__(256) void soft_tx(const __bf16* __restrict__ SC,
                                               __bf16* __restrict__ adjh,
                                               const float* __restrict__ x,
                                               __bf16* __restrict__ XT,
                                               __bf16* __restrict__ xbf) {
  const int tid = threadIdx.x;
  if (blockIdx.x < 2048) {
    const int wave = tid >> 6, lane = tid & 63;
    const size_t row = (size_t)blockIdx.x * 4 + wave;
    const __bf16* src = SC + row * NNODE;
    __bf16* dst = adjh + row * NNODE;
    float v[32];
    float mx = 0.f;
#pragma unroll
    for (int j = 0; j < 4; ++j) {
      bf16x8 q = *(const bf16x8*)(src + j * 512 + lane * 8);
#pragma unroll
      for (int i = 0; i < 8; ++i) {
        float f = (float)q[i];
        v[j * 8 + i] = f;
        mx = fmaxf(mx, f);
      }
    }
#pragma unroll
    for (int o = 32; o > 0; o >>= 1) mx = fmaxf(mx, __shfl_xor(mx, o));
    float s = 0.f;
#pragma unroll
    for (int i = 0; i < 32; ++i) {
      v[i] = __expf(v[i] - mx);
      s += v[i];
    }
#pragma unroll
    for (int o = 32; o > 0; o >>= 1) s += __shfl_xor(s, o);
    float inv = 1.f / s;
#pragma unroll
    for (int j = 0; j < 4; ++j) {
      bf16x8 q;
#pragma unroll
      for (int i = 0; i < 8; ++i) q[i] = (__bf16)(v[j * 8 + i] * inv);
      *(bf16x8*)(dst + j * 512 + lane * 8) = q;
    }
  } else {
    const int idx = blockIdx.x - 2048;
    const int b = idx >> 5, v0 = (idx & 31) * 64;
    __shared__ float t[64][65];
    const int vr = tid >> 2, c0 = (tid & 3) * 16;
    const float* src = x + ((size_t)b * NNODE + v0 + vr) * 64 + c0;
    __bf16* xb = xbf + ((size_t)b * NNODE + v0 + vr) * 64 + c0;
#pragma unroll
    for (int j = 0; j < 4; ++j) {
      float4 q = ((const float4*)src)[j];
      t[vr][c0 + j * 4 + 0] = q.x;
      t[vr][c0 + j * 4 + 1] = q.y;
      t[vr][c0 + j * 4 + 2] = q.z;
      t[vr][c0 + j * 4 + 3] = q.w;
      xb[j * 4 + 0] = (__bf16)q.x;
      xb[j * 4 + 1] = (__bf16)q.y;
      xb[j * 4 + 2] = (__bf16)q.z;
      xb[j * 4 + 3] = (__bf16)q.w;
    }
    __syncthreads();
#pragma unroll
    for (int jr = 0; jr < 16; ++jr) {
      int c = jr * 4 + (tid >> 6);
      int v = tid & 63;
      XT[((size_t)b * 64 + c) * NNODE + v0 + v] = (__bf16)t[v][c];
    }
  }
}

// ---------------------------------------------------------------------------
// Fused adjacency prep: ADJ bf16, w-scaled ADJT, M1 accum. (R8-verified)
__global__ __launch_bounds__(256) void prep_adj(const float* __restrict__ A1,
                                                const float* __restrict__ A2,
                                                __bf16* __restrict__ ADJ,
                                                __bf16* __restrict__ ADJT,
                                                __bf16* __restrict__ M1,
                                                const float* __restrict__ wpre,
                                                const float* __restrict__ wadp) {
  const int r0 = blockIdx.x * 64, c0 = blockIdx.y * 64;
  const int tid = threadIdx.x;
  const size_t NN2 = (size_t)NNODE * NNODE;
  const float wp = *wpre, wa = *wadp * 0.25f;
  __shared__ float t[64][65];
  const int vr = tid >> 2, cg = (tid & 3) * 16;
  float m1acc[16] = {};

  for (int z = 0; z < 6; ++z) {
    const float wz = (z < 2) ? wp : wa;
    float vv[16];
    if (z < 2) {
      const float* src = (z == 0 ? A1 : A2) + (size_t)(r0 + vr) * NNODE + c0 + cg;
#pragma unroll
      for (int j = 0; j < 4; ++j) {
        float4 q = ((const float4*)src)[j];
        vv[j * 4 + 0] = q.x; vv[j * 4 + 1] = q.y;
        vv[j * 4 + 2] = q.z; vv[j * 4 + 3] = q.w;
      }
      __bf16* q = ADJ + (size_t)z * NN2 + (size_t)(r0 + vr) * NNODE + c0 + cg;
      bf16x8 o0, o1;
#pragma unroll
      for (int i = 0; i < 8; ++i) { o0[i] = (__bf16)vv[i]; o1[i] = (__bf16)vv[8 + i]; }
      ((bf16x8*)q)[0] = o0;
      ((bf16x8*)q)[1] = o1;
    } else {
      const __bf16* p = ADJ + (size_t)z * NN2 + (size_t)(r0 + vr) * NNODE + c0 + cg;
      bf16x8 q0 = ((const bf16x8*)p)[0];
      bf16x8 q1 = ((const bf16x8*)p)[1];
#pragma unroll
      for (int i = 0; i < 8; ++i) { vv[i] = (float)q0[i]; vv[8 + i] = (float)q1[i]; }
    }
#pragma unroll
    for (int i = 0; i < 16; ++i) {
      m1acc[i] += wz * vv[i];
      t[vr][cg + i] = vv[i];
    }
    __syncthreads();
#pragma unroll
    for (int jr = 0; jr < 16; ++jr) {
      int c = jr * 4 + (tid >> 6);
      int v = tid & 63;
      ADJT[(size_t)z * NN2 + (size_t)(c0 + c) * NNODE + r0 + v] = (__bf16)(wz * t[v][c]);
    }
    __syncthreads();
  }
  __bf16* q = M1 + (size_t)(r0 + vr) * NNODE + c0 + cg;
  bf16x8 o0, o1;
#pragma unroll
  for (int i = 0; i < 8; ++i) { o0[i] = (__bf16)m1acc[i]; o1[i] = (__bf16)m1acc[8 + i]; }
  ((bf16x8*)q)[0] = o0;
  ((bf16x8*)q)[1] = o1;
}

// ---------------------------------------------------------------------------
// Shared GEMM machinery (R11-verified): 128x128, BK=64, 4 waves, 2 blocks/CU,
// counted vmcnt(8), 3-bit XOR swizzle, register-double-buffered pipeline.
#define VMCNT0() asm volatile("s_waitcnt vmcnt(0)" ::: "memory")
#define VMCNT8() asm volatile("s_waitcnt vmcnt(8)" ::: "memory")
#define LGKMCNT0() asm volatile("s_waitcnt lgkmcnt(0)" ::: "memory")
#define BARRIER() asm volatile("s_barrier" ::: "memory")

#define READFRAGS(d, AF, BF)                                                  \
  do {                                                                        \
    _Pragma("unroll")                                                         \
    for (int mi = 0; mi < 4; ++mi) {                                          \
      AF[mi][0] = *(const bf16x8*)(AREG(d) + aoff[mi][0]);                    \
      AF[mi][1] = *(const bf16x8*)(AREG(d) + aoff[mi][1]);                    \
    }                                                                         \
    _Pragma("unroll")                                                         \
    for (int j = 0; j < 4; ++j) {                                             \
      BF[j][0] = *(const bf16x8*)(BREG(d) + boff[j][0]);                      \
      BF[j][1] = *(const bf16x8*)(BREG(d) + boff[j][1]);                      \
    }                                                                         \
  } while (0)

#define MFMA16(AF, BF)                                                        \
  do {                                                                        \
    __builtin_amdgcn_s_setprio(1);                                            \
    _Pragma("unroll")                                                         \
    for (int mi = 0; mi < 4; ++mi)                                            \
      _Pragma("unroll")                                                       \
      for (int j = 0; j < 4; ++j)                                             \
        _Pragma("unroll")                                                     \
        for (int ks = 0; ks < 2; ++ks)                                        \
          acc[mi][j] = __builtin_amdgcn_mfma_f32_16x16x32_bf16(               \
              AF[mi][ks], BF[j][ks], acc[mi][j], 0, 0, 0);                    \
    __builtin_amdgcn_s_setprio(0);                                            \
  } while (0)

// Fused-squares: M2part[zh] = sum_{z in half} ADJ_z @ ADJT_z^T (ADJT w-scaled),
// f32 partials. 96 K-tiles/block. XCD-chunked block swizzle.
__global__ __launch_bounds__(256, 2) void gemm_sq(const __bf16* __restrict__ ADJ,
                                                  const __bf16* __restrict__ ADJT,
                                                  float* __restrict__ M2part) {
  extern __shared__ char smem[];  // 65536 B
  const int tid = threadIdx.x;
  const int w = tid >> 6, l = tid & 63;
  const int wr = w >> 1, wc = w & 1;
  const size_t NN2 = (size_t)NNODE * NNODE;
  const size_t NN2B2 = NN2 * 2;
  int lin = blockIdx.x + 16 * blockIdx.y + 256 * blockIdx.z;
  int nlin = (lin & 7) * 64 + (lin >> 3);
  const int m0 = (nlin & 15) * 128, n0 = ((nlin >> 4) & 15) * 128;
  const int zh = nlin >> 8;
  const int zb = zh * 3;
  float* Cp = M2part + (size_t)zh * NN2;
  const int NTT = 96;  // 3 z * 32 K-tiles

#define AREG(d) (smem + (d) * 16384)
#define BREG(d) (smem + 32768 + (d) * 16384)

  int aoff[4][2], boff[4][2];
#pragma unroll
  for (int mi = 0; mi < 4; ++mi)
#pragma unroll
    for (int ks = 0; ks < 2; ++ks) {
      int rh = mi * 32 + wr * 16 + (l & 15);
      int lo = rh * 128 + ks * 64 + ((l >> 4) * 16);
      aoff[mi][ks] = lo ^ ((rh & 7) << 4);
    }
#pragma unroll
  for (int j = 0; j < 4; ++j)
#pragma unroll
    for (int ks = 0; ks < 2; ++ks) {
      int rh = j * 32 + wc * 16 + (l & 15);
      int lo = rh * 128 + ks * 64 + ((l >> 4) * 16);
      boff[j][ks] = lo ^ ((rh & 7) << 4);
    }

  const int sg_row = w * 8 + (l >> 3);
  const int sg_col = (((l & 7) ^ ((l >> 3) & 7)) << 4);
  unsigned aLoff[4], bLoff[4];
#pragma unroll
  for (int p = 0; p < 4; ++p) {
    aLoff[p] = (unsigned)((m0 + p * 32 + sg_row) * 4096 + sg_col);
    bLoff[p] = (unsigned)((n0 + p * 32 + sg_row) * 4096 + sg_col);
  }

#define STAGEOFF(toff, region)                                                \
  do {                                                                        \
    _Pragma("unroll")                                                         \
    for (int p = 0; p < 4; ++p)                                               \
      gload16((const char*)ADJ + (toff) + aLoff[p],                           \
              (region) + p * 4096 + w * 1024);                                \
  } while (0)
#define STAGEOFFB(toff, region)                                               \
  do {                                                                        \
    _Pragma("unroll")                                                         \
    for (int p = 0; p < 4; ++p)                                               \
      gload16((const char*)ADJT + (toff) + bLoff[p],                          \
              (region) + p * 4096 + w * 1024);                                \
  } while (0)

  f32x4 acc[4][4] = {};
  bf16x8 afA[4][2], bfA[4][2], afB[4][2], bfB[4][2];

  // prologue: tiles 0,1 staged; frags(0) read into A-set
  size_t tOff = (size_t)zb * NN2B2;
  STAGEOFF(tOff, AREG(0));
  STAGEOFFB(tOff, BREG(0));
  STAGEOFF(tOff + 128, AREG(1));
  STAGEOFFB(tOff + 128, BREG(1));
  tOff += 256;
  VMCNT8();   // tile0 landed
  BARRIER();
  READFRAGS(0, afA, bfA);
  LGKMCNT0();
  BARRIER();  // all waves done reading buf0 -> loop may overwrite it

  for (int t = 0; t <= NTT - 4; t += 2) {
    STAGEOFF(tOff, AREG(0));
    STAGEOFFB(tOff, BREG(0));
    tOff += (((t + 2) & 31) == 31) ? (NN2B2 - (size_t)31 * 128) : (size_t)128;
    VMCNT8();
    BARRIER();
    READFRAGS(1, afB, bfB);
    MFMA16(afA, bfA);
    LGKMCNT0();
    BARRIER();
    STAGEOFF(tOff, AREG(1));
    STAGEOFFB(tOff, BREG(1));
    tOff += (((t + 3) & 31) == 31) ? (NN2B2 - (size_t)31 * 128) : (size_t)128;
    VMCNT8();
    BARRIER();
    READFRAGS(0, afA, bfA);
    MFMA16(afB, bfB);
    LGKMCNT0();
    BARRIER();
  }
  VMCNT0();
  BARRIER();
  READFRAGS(1, afB, bfB);
  MFMA16(afA, bfA);
  LGKMCNT0();
  MFMA16(afB, bfB);

  const int crow = (l >> 4) * 4;
  const int ccol = l & 15;
#pragma unroll
  for (int mi = 0; mi < 4; ++mi)
#pragma unroll
    for (int j = 0; j < 4; ++j) {
      int r0 = m0 + mi * 32 + wr * 16 + crow;
      int cc = n0 + j * 32 + wc * 16 + ccol;
#pragma unroll
      for (int r = 0; r < 4; ++r)
        Cp[(size_t)(r0 + r) * NNODE + cc] = acc[mi][j][r];
    }
#undef STAGEOFF
#undef STAGEOFFB
#undef AREG
#undef BREG
}

// ---------------------------------------------------------------------------
// Stage GEMM with fused transposed epilogue (R9-verified epilogue), R11
// register-pipelined K-loop.
__global__ __launch_bounds__(256, 2) void gemm_hop1s(const __bf16* __restrict__ XT,
                                                     const __bf16* __restrict__ MMb,
                                                     __bf16* __restrict__ S1,
                                                     __bf16* __restrict__ S2) {
  extern __shared__ char smem[];  // 65536 B
  const int tid = threadIdx.x;
  const int w = tid >> 6, l = tid & 63;
  const int wr = w >> 1, wc = w & 1;
  const size_t NN2 = (size_t)NNODE * NNODE;
  int lin = blockIdx.x + 16 * blockIdx.y + 256 * blockIdx.z;
  int nlin = (lin & 7) * 64 + (lin >> 3);
  const int m0 = (nlin & 15) * 128, n0 = ((nlin >> 4) & 15) * 128;
  const int z = nlin >> 8;
  const char* Abase = (const char*)XT;
  const char* Bbase = (const char*)(MMb + (size_t)z * NN2);
  const int NT = NNODE / 64;  // 32

#define AREG(d) (smem + (d) * 16384)
#define BREG(d) (smem + 32768 + (d) * 16384)

  int aoff[4][2], boff[4][2];
#pragma unroll
  for (int mi = 0; mi < 4; ++mi)
#pragma unroll
    for (int ks = 0; ks < 2; ++ks) {
      int rh = mi * 32 + wr * 16 + (l & 15);
      int lo = rh * 128 + ks * 64 + ((l >> 4) * 16);
      aoff[mi][ks] = lo ^ ((rh & 7) << 4);
    }
#pragma unroll
  for (int j = 0; j < 4; ++j)
#pragma unroll
    for (int ks = 0; ks < 2; ++ks) {
      int rh = j * 32 + wc * 16 + (l & 15);
      int lo = rh * 128 + ks * 64 + ((l >> 4) * 16);
      boff[j][ks] = lo ^ ((rh & 7) << 4);
    }

  const int sg_row = w * 8 + (l >> 3);
  const int sg_col = (((l & 7) ^ ((l >> 3) & 7)) << 4);
  unsigned aLoff[4], bLoff[4];
#pragma unroll
  for (int p = 0; p < 4; ++p) {
    aLoff[p] = (unsigned)((m0 + p * 32 + sg_row) * 4096 + sg_col);
    bLoff[p] = (unsigned)((n0 + p * 32 + sg_row) * 4096 + sg_col);
  }

#define STAGEA(koff, region)                                                  \
  do {                                                                        \
    _Pragma("unroll")                                                         \
    for (int p = 0; p < 4; ++p)                                               \
      gload16(Abase + (koff) + aLoff[p], (region) + p * 4096 + w * 1024);     \
  } while (0)
#define STAGEB(koff, region)                                                  \
  do {                                                                        \
    _Pragma("unroll")                                                         \
    for (int p = 0; p < 4; ++p)                                               \
      gload16(Bbase + (koff) + bLoff[p], (region) + p * 4096 + w * 1024);     \
  } while (0)

  f32x4 acc[4][4] = {};
  bf16x8 afA[4][2], bfA[4][2], afB[4][2], bfB[4][2];

  size_t kOff = 0;
  STAGEA(kOff, AREG(0));
  STAGEB(kOff, BREG(0));
  STAGEA(kOff + 128, AREG(1));
  STAGEB(kOff + 128, BREG(1));
  kOff += 256;
  VMCNT8();
  BARRIER();
  READFRAGS(0, afA, bfA);
  LGKMCNT0();
  BARRIER();

  for (int t = 0; t <= NT - 4; t += 2) {
    STAGEA(kOff, AREG(0));
    STAGEB(kOff, BREG(0));
    kOff += 128;
    VMCNT8();
    BARRIER();
    READFRAGS(1, afB, bfB);
    MFMA16(afA, bfA);
    LGKMCNT0();
    BARRIER();
    STAGEA(kOff, AREG(1));
    STAGEB(kOff, BREG(1));
    kOff += 128;
    VMCNT8();
    BARRIER();
    READFRAGS(0, afA, bfA);
    MFMA16(afB, bfB);
    LGKMCNT0();
    BARRIER();
  }
  VMCNT0();
  BARRIER();
  READFRAGS(1, afB, bfB);
  MFMA16(afA, bfA);
  LGKMCNT0();
  MFMA16(afB, bfB);

  // ---- epilogue (R9-verified): LDS transpose T[n][m] with slot-XOR swizzle,
  // coalesced write S_z[(b, n0+n)*64 + c].
  {
    __syncthreads();  // all LDS reads done before reusing smem as T
    const int crow = (l >> 4) * 4;
    const int ccol = l & 15;
    char* T = smem;  // 128 x 256 B = 32 KiB
#pragma unroll
    for (int mi = 0; mi < 4; ++mi)
#pragma unroll
      for (int j = 0; j < 4; ++j) {
        int ml = mi * 32 + wr * 16 + crow;
        int nl = j * 32 + wc * 16 + ccol;
        bf16x4 v;
#pragma unroll
        for (int r = 0; r < 4; ++r) v[r] = (__bf16)acc[mi][j][r];
        *(bf16x4*)(T + nl * 256 + ((ml * 2) ^ ((nl & 7) << 4))) = v;
      }
    __syncthreads();
    __bf16* dst = z ? S2 : S1;
    const int bA = m0 >> 6;
#pragma unroll
    for (int it = 0; it < 4; ++it) {
      int nl = (tid >> 3) + it * 32;
      int seg = tid & 7;
      int xorv = (nl & 7) << 4;
      const char* src = T + nl * 256;
      bf16x8 v0 = *(const bf16x8*)(src + ((seg * 32) ^ xorv));
      bf16x8 v1 = *(const bf16x8*)(src + ((seg * 32 + 16) ^ xorv));
      int b = bA + (seg >> 2);
      size_t o = ((size_t)b * NNODE + n0 + nl) * 64 + (seg & 3) * 16;
      *(bf16x8*)(dst + o) = v0;
      *(bf16x8*)(dst + o + 8) = v1;
    }
  }
#undef STAGEA
#undef STAGEB
#undef AREG
#undef BREG
}

// ---------------------------------------------------------------------------
// M2[i] = (bf16)(M2a[i] + M2b[i])
__global__ __launch_bounds__(256) void combine_m2(const float* __restrict__ M2p,
                                                  __bf16* __restrict__ M2) {
  const size_t NN2 = (size_t)NNODE * NNODE;
  size_t i = ((size_t)blockIdx.x * 256 + threadIdx.x) * 4;
  float4 a = *(const float4*)(M2p + i);
  float4 b = *(const float4*)(M2p + NN2 + i);
  M2[i + 0] = (__bf16)(a.x + b.x);
  M2[i + 1] = (__bf16)(a.y + b.y);
  M2[i + 2] = (__bf16)(a.z + b.z);
  M2[i + 3] = (__bf16)(a.w + b.w);
}

// ---------------------------------------------------------------------------
// Gate linear GEMM: [65536 x 192] @ Wt^T, K=192, N=128, fused epilogues.
// MODE 0: cols 0-63 -> z=sigmoid -> zbuf(f32); cols 64-127 -> r ->
//         rx=(bf16)(r*hid) row-major AND rxT -> XTout via LDS transpose.
// MODE 1: cols 0-63 -> c=tanh -> out=(1-z)*hid+z*c (f32)
template <int MODE>
__global__ __launch_bounds__(256) void gemm_lin(const __bf16* __restrict__ Xp,
                                                const __bf16* __restrict__ S1,
                                                const __bf16* __restrict__ S2,
                                                const __bf16* __restrict__ Wt,
                                                const float* __restrict__ b0,
                                                const float* __restrict__ b1,
                                                const float* __restrict__ wpre,
                                                const float* __restrict__ wadp,
                                                const float* __restrict__ hid,
                                                float* __restrict__ zbuf,
                                                __bf16* __restrict__ rxout,
                                                __bf16* __restrict__ XTout,
                                                float* __restrict__ outp) {
  __shared__ __bf16 As[128 * 32];
  __shared__ __bf16 Bs[128 * 32];
  __shared__ char T[64 * 256];  // rx transpose staging (MODE 0)
  const int tid = threadIdx.x;
  const int wave = tid >> 6, lane = tid & 63;
  const int wr = wave >> 1, wc = wave & 1;
  const int m0 = blockIdx.x * 128;
  const int rowA = tid >> 2;
  const int colb = (tid & 3) * 16;
  const __bf16* srcs[3] = {Xp, S1, S2};
  char* asD0 = (char*)As + wave * 1024;
  char* asD1 = (char*)As + 4096 + wave * 1024;
  char* bsD0 = (char*)Bs + wave * 1024;
  char* bsD1 = (char*)Bs + 4096 + wave * 1024;

  f32x4 acc[4][4] = {};

#pragma unroll
  for (int kt = 0; kt < 6; ++kt) {
    const __bf16* Ab = srcs[kt >> 1];
    const char* aS0 = (const char*)(Ab + (size_t)(m0 + rowA) * 64) + (kt & 1) * 64 + colb;
    const char* aS1 = (const char*)(Ab + (size_t)(m0 + rowA + 64) * 64) + (kt & 1) * 64 + colb;
    const char* bS0 = (const char*)(Wt + (size_t)rowA * 192) + kt * 64 + colb;
    const char* bS1 = (const char*)(Wt + (size_t)(rowA + 64) * 192) + kt * 64 + colb;
    gload16(aS0, asD0);
    gload16(aS1, asD1);
    gload16(bS0, bsD0);
    gload16(bS1, bsD1);
    __syncthreads();
    bf16x8 af[4], bfr[4];
#pragma unroll
    for (int mi = 0; mi < 4; ++mi)
      af[mi] = *(const bf16x8*)((const char*)As +
               ((wr * 64 + mi * 16 + (lane & 15)) * 64 + (lane >> 4) * 16));
#pragma unroll
    for (int ni = 0; ni < 4; ++ni)
      bfr[ni] = *(const bf16x8*)((const char*)Bs +
               ((wc * 64 + ni * 16 + (lane & 15)) * 64 + (lane >> 4) * 16));
#pragma unroll
    for (int mi = 0; mi < 4; ++mi)
#pragma unroll
      for (int ni = 0; ni < 4; ++ni)
        acc[mi][ni] = __builtin_amdgcn_mfma_f32_16x16x32_bf16(af[mi], bfr[ni],
                                                              acc[mi][ni], 0, 0, 0);
    __syncthreads();
  }

  const float wp = *wpre, wa = *wadp;
  const float s = 2.f * wp + wa;
  const int crow = (lane >> 4) * 4;
  const int ccol = lane & 15;
#pragma unroll
  for (int mi = 0; mi < 4; ++mi)
#pragma unroll
    for (int ni = 0; ni < 4; ++ni) {
      int r0 = m0 + wr * 64 + mi * 16 + crow;
      int col = wc * 64 + ni * 16 + ccol;
      int cf = col & 63;
      if (MODE == 0) {
        if (col < 64) {
#pragma unroll
          for (int r = 0; r < 4; ++r) {
            int row = r0 + r;
            float g = acc[mi][ni][r] + s * b0[cf];
            zbuf[(size_t)row * 64 + cf] = 1.f / (1.f + __expf(-g));
          }
        } else {
          bf16x4 tv;
#pragma unroll
          for (int r = 0; r < 4; ++r) {
            int row = r0 + r;
            float g = acc[mi][ni][r] + s * b1[cf];
            float rv = 1.f / (1.f + __expf(-g));
            __bf16 rxv = (__bf16)(rv * hid[(size_t)row * 64 + cf]);
            rxout[(size_t)row * 64 + cf] = rxv;
            tv[r] = rxv;
          }
          int vl0 = wr * 64 + mi * 16 + crow;  // local v base (4 consecutive)
          *(bf16x4*)(T + cf * 256 + ((vl0 * 2) ^ ((cf & 7) << 4))) = tv;
        }
      } else {
        if (col < 64) {
#pragma unroll
          for (int r = 0; r < 4; ++r) {
            int row = r0 + r;
            float g = acc[mi][ni][r] + s * b0[cf];
            float cv = 1.f - 2.f / (1.f + __expf(2.f * g));
            float zv = zbuf[(size_t)row * 64 + cf];
            float hv = hid[(size_t)row * 64 + cf];
            outp[(size_t)row * 64 + cf] = (1.f - zv) * hv + zv * cv;
          }
        }
      }
    }

  if (MODE == 0) {
    // write rx^T into XTout[(b*64+c)*2048 + v0 + v], coalesced 256B rows
    __syncthreads();
    const int b = m0 >> 11;       // batch of this 128-row tile
    const int v0 = m0 & 2047;
#pragma unroll
    for (int it = 0; it < 4; ++it) {
      int rr = it * 16 + (tid >> 4);   // c row 0..63
      int seg = tid & 15;              // 16B segment within 256B row
      bf16x8 v = *(const bf16x8*)(T + rr * 256 + ((seg * 16) ^ ((rr & 7) << 4)));
      *(bf16x8*)(XTout + ((size_t)(b * 64 + rr)) * NNODE + v0 + seg * 8) = v;
    }
  }
}

// ---------------------------------------------------------------------------
extern "C" void kernel_launch(void* const* d_in, const int* in_sizes, int n_in,
                              void* d_out, int out_size, void* d_ws, size_t ws_size,
                              hipStream_t stream) {
  (void)in_sizes; (void)n_in; (void)out_size;
  const float* x    = (const float*)d_in[0];
  const float* A1   = (const float*)d_in[1];
  const float* A2   = (const float*)d_in[2];
  const float* E1   = (const float*)d_in[3];
  const float* E2   = (const float*)d_in[4];
  const float* Wz   = (const float*)d_in[5];
  const float* bz   = (const float*)d_in[6];
  const float* Wr   = (const float*)d_in[7];
  const float* br   = (const float*)d_in[8];
  const float* Wc   = (const float*)d_in[9];
  const float* bc   = (const float*)d_in[10];
  const float* wpre = (const float*)d_in[11];
  const float* wadp = (const float*)d_in[12];
  float* out = (float*)d_out;

  char* ws = (char*)d_ws;
  const size_t NN2 = (size_t)NNODE * NNODE;  // 4,194,304 (= B*N*D too)
  const size_t NN2B = NN2 * 2;               // bytes per bf16 slice
  __bf16* ADJ  = (__bf16*)(ws);                 // [0,6) bf16 slices
  __bf16* ADJT = (__bf16*)(ws + 6 * NN2B);      // [6,12) w-scaled transposes
  __bf16* SC   = (__bf16*)(ws + 12 * NN2B);     // scores (4 slices), then:
  float*  M2p  = (float*)(ws + 12 * NN2B);      // f32 partials x2 = [12,16)
  __bf16* MM   = (__bf16*)(ws + 18 * NN2B);     // M1 @18, M2 @19
  __bf16* XT   = (__bf16*)(ws + 20 * NN2B);
  __bf16* xbf  = (__bf16*)(ws + 21 * NN2B);
  __bf16* rx   = (__bf16*)(ws + 22 * NN2B);
  __bf16* S1   = (__bf16*)(ws + 2 * NN2B);      // over ADJ[2] (dead post-sq)
  __bf16* S2   = (__bf16*)(ws + 3 * NN2B);      // over ADJ[3]
  float*  zbuf = (float*)(ws + 4 * NN2B);       // over ADJ[4..5]
  __bf16* E1p  = (__bf16*)(ws + 23 * NN2B);
  __bf16* E2p  = E1p + 4 * NNODE * 32;
  __bf16* Wzrt = E2p + 4 * NNODE * 32;
  __bf16* Wct  = Wzrt + 128 * 192;
  if (ws_size < 23 * NN2B + 2 * 4 * NNODE * 32 * 2 + 2 * 128 * 192 * 2) return;

  // --- adjacency construction (fused)
  prep_ew<<<224, 256, 0, stream>>>(E1, E2, Wz, Wr, Wc, wpre, wadp,
                                   E1p, E2p, Wzrt, Wct);
  score_gemm<<<dim3(16, 16, 4), 256, 0, stream>>>(E1p, E2p, SC);
  soft_tx<<<3072, 256, 0, stream>>>(SC, ADJ + 2 * NN2, x, XT, xbf);
  prep_adj<<<dim3(32, 32), 256, 0, stream>>>(A1, A2, ADJ, ADJT, MM, wpre, wadp);

  // --- M2 = sum_z w_z A_z^2 (fused accumulate; 512 blocks, XCD-chunked)
  gemm_sq<<<dim3(16, 16, 2), 256, 65536, stream>>>(ADJ, ADJT, M2p);
  combine_m2<<<4096, 256, 0, stream>>>(M2p, MM + NN2);

  // --- stage 1: S1 = M1 x, S2 = M2 x (fused transposed epilogue)
  gemm_hop1s<<<dim3(16, 16, 2), 256, 65536, stream>>>(XT, MM, S1, S2);
  gemm_lin<0><<<512, 256, 0, stream>>>(xbf, S1, S2, Wzrt, bz, br, wpre, wadp,
                                       x, zbuf, rx, XT, nullptr);

  // --- stage 2: hops on r*x (XT already holds rx^T from gemm_lin<0>)
  gemm_hop1s<<<dim3(16, 16, 2), 256, 65536, stream>>>(XT, MM, S1, S2);
  gemm_lin<1><<<512, 256, 0, stream>>>(rx, S1, S2, Wct, bc, nullptr, wpre, wadp,
                                       x, zbuf, nullptr, nullptr, out);
}

// Round 13
// 229.163 us; speedup vs baseline: 1.1930x; 1.1105x over previous
//
#include <hip/hip_runtime.h>

#define NNODE 2048
#define NBATCH 32

typedef __attribute__((ext_vector_type(4))) float f32x4;
typedef __attribute__((ext_vector_type(8))) __bf16 bf16x8;
typedef __attribute__((ext_vector_type(4))) __bf16 bf16x4;

__device__ __forceinline__ void gload16(const void* g, void* lds) {
  __builtin_amdgcn_global_load_lds(
      (const __attribute__((address_space(1))) unsigned int*)g,
      (__attribute__((address_space(3))) unsigned int*)lds, 16, 0, 0);
}

// ---------------------------------------------------------------------------
// Merged: prep_e (blocks 0..127) + prep_w (blocks 128..223)
__global__ __launch_bounds__(256) void prep_ew(const float* __restrict__ E1,
                                               const float* __restrict__ E2,
                                               const float* __restrict__ Wz,
                                               const float* __restrict__ Wr,
                                               const float* __restrict__ Wc,
                                               const float* __restrict__ wpre,
                                               const float* __restrict__ wadp,
                                               __bf16* __restrict__ E1p,
                                               __bf16* __restrict__ E2p,
                                               __bf16* __restrict__ Wzrt,
                                               __bf16* __restrict__ Wct) {
  if (blockIdx.x < 128) {
    int idx = blockIdx.x * 256 + threadIdx.x;  // 0..32767
    int cq = idx & 3;
    int n = (idx >> 2) & 2047;
    int h = idx >> 13;
    const float4 q1 = *(const float4*)(E1 + (size_t)(n * 4 + h) * 16 + cq * 4);
    const float4 q2 = *(const float4*)(E2 + (size_t)(n * 4 + h) * 16 + cq * 4);
    size_t o = ((size_t)h * NNODE + n) * 32 + cq * 4;
    E1p[o + 0] = (__bf16)q1.x; E1p[o + 1] = (__bf16)q1.y;
    E1p[o + 2] = (__bf16)q1.z; E1p[o + 3] = (__bf16)q1.w;
    E2p[o + 0] = (__bf16)q2.x; E2p[o + 1] = (__bf16)q2.y;
    E2p[o + 2] = (__bf16)q2.z; E2p[o + 3] = (__bf16)q2.w;
    size_t oz = o + 16;
    E1p[oz + 0] = (__bf16)0.f; E1p[oz + 1] = (__bf16)0.f;
    E1p[oz + 2] = (__bf16)0.f; E1p[oz + 3] = (__bf16)0.f;
    E2p[oz + 0] = (__bf16)0.f; E2p[oz + 1] = (__bf16)0.f;
    E2p[oz + 2] = (__bf16)0.f; E2p[oz + 3] = (__bf16)0.f;
  } else {
    int idx = (blockIdx.x - 128) * 256 + threadIdx.x;  // 0 .. 128*192-1
    int rr = idx / 192, k = idx % 192;
    float s = 2.f * (*wpre) + (*wadp);
    float sc = (k < 64) ? s : 1.f;
    float vz = (rr < 64) ? Wz[(size_t)k * 64 + rr] : Wr[(size_t)k * 64 + rr - 64];
    Wzrt[idx] = (__bf16)(vz * sc);
    float vc = (rr < 64) ? Wc[(size_t)k * 64 + rr] * sc : 0.f;
    Wct[idx] = (__bf16)vc;
  }
}

// ---------------------------------------------------------------------------
// SC[h][w][v] = relu(E1p_h @ E2p_h^T)/4, bf16. Single K=32 MFMA step.
__global__ __launch_bounds__(256) void score_gemm(const __bf16* __restrict__ E1p,
                                                  const __bf16* __restrict__ E2p,
                                                  __bf16* __restrict__ SC) {
  __shared__ __bf16 As[128 * 32];
  __shared__ __bf16 Bs[128 * 32];
  const int tid = threadIdx.x;
  const int wave = tid >> 6, lane = tid & 63;
  const int wr = wave >> 1, wc = wave & 1;
  const int h = blockIdx.z;
  const int m0 = blockIdx.x * 128, n0 = blockIdx.y * 128;
  const __bf16* A = E1p + (size_t)h * NNODE * 32;
  const __bf16* Bt = E2p + (size_t)h * NNODE * 32;
  const int rowA = tid >> 2;
  const int colb = (tid & 3) * 16;
  gload16((const char*)(A + (size_t)(m0 + rowA) * 32) + colb, (char*)As + wave * 1024);
  gload16((const char*)(A + (size_t)(m0 + rowA + 64) * 32) + colb, (char*)As + 4096 + wave * 1024);
  gload16((const char*)(Bt + (size_t)(n0 + rowA) * 32) + colb, (char*)Bs + wave * 1024);
  gload16((const char*)(Bt + (size_t)(n0 + rowA + 64) * 32) + colb, (char*)Bs + 4096 + wave * 1024);
  __syncthreads();

  f32x4 acc[4][4] = {};
  bf16x8 af[4], bfr[4];
#pragma unroll
  for (int mi = 0; mi < 4; ++mi)
    af[mi] = *(const bf16x8*)((const char*)As +
             ((wr * 64 + mi * 16 + (lane & 15)) * 64 + (lane >> 4) * 16));
#pragma unroll
  for (int ni = 0; ni < 4; ++ni)
    bfr[ni] = *(const bf16x8*)((const char*)Bs +
             ((wc * 64 + ni * 16 + (lane & 15)) * 64 + (lane >> 4) * 16));
#pragma unroll
  for (int mi = 0; mi < 4; ++mi)
#pragma unroll
    for (int ni = 0; ni < 4; ++ni)
      acc[mi][ni] = __builtin_amdgcn_mfma_f32_16x16x32_bf16(af[mi], bfr[ni],
                                                            acc[mi][ni], 0, 0, 0);

  const int crow = (lane >> 4) * 4;
  const int ccol = lane & 15;
#pragma unroll
  for (int mi = 0; mi < 4; ++mi)
#pragma unroll
    for (int ni = 0; ni < 4; ++ni) {
      int r0 = m0 + wr * 64 + mi * 16 + crow;
      int cc = n0 + wc * 64 + ni * 16 + ccol;
#pragma unroll
      for (int r = 0; r < 4; ++r) {
        float val = fmaxf(acc[mi][ni][r], 0.f) * 0.25f;
        SC[((size_t)h * NNODE + r0 + r) * NNODE + cc] = (__bf16)val;
      }
    }
}

// ---------------------------------------------------------------------------
// Merged: blocks 0..2047 -> row softmax (SC -> adjh); blocks 2048..3071 ->
// transpose_x (x f32 [B,N,64] -> XT bf16 [B*64,N] and xbf bf16 [B*N,64]).
__global__ __launch_bounds__(256) void soft_tx(const __bf16* __restrict__ SC,
                                               __bf16* __restrict__ adjh,
                                               const float* __restrict__ x,
                                               __bf16* __restrict__ XT,
                                               __bf16* __restrict__ xbf) {
  const int tid = threadIdx.x;
  if (blockIdx.x < 2048) {
    const int wave = tid >> 6, lane = tid & 63;
    const size_t row = (size_t)blockIdx.x * 4 + wave;
    const __bf16* src = SC + row * NNODE;
    __bf16* dst = adjh + row * NNODE;
    float v[32];
    float mx = 0.f;
#pragma unroll
    for (int j = 0; j < 4; ++j) {
      bf16x8 q = *(const bf16x8*)(src + j * 512 + lane * 8);
#pragma unroll
      for (int i = 0; i < 8; ++i) {
        float f = (float)q[i];
        v[j * 8 + i] = f;
        mx = fmaxf(mx, f);
      }
    }
#pragma unroll
    for (int o = 32; o > 0; o >>= 1) mx = fmaxf(mx, __shfl_xor(mx, o));
    float s = 0.f;
#pragma unroll
    for (int i = 0; i < 32; ++i) {
      v[i] = __expf(v[i] - mx);
      s += v[i];
    }
#pragma unroll
    for (int o = 32; o > 0; o >>= 1) s += __shfl_xor(s, o);
    float inv = 1.f / s;
#pragma unroll
    for (int j = 0; j < 4; ++j) {
      bf16x8 q;
#pragma unroll
      for (int i = 0; i < 8; ++i) q[i] = (__bf16)(v[j * 8 + i] * inv);
      *(bf16x8*)(dst + j * 512 + lane * 8) = q;
    }
  } else {
    const int idx = blockIdx.x - 2048;
    const int b = idx >> 5, v0 = (idx & 31) * 64;
    __shared__ float t[64][65];
    const int vr = tid >> 2, c0 = (tid & 3) * 16;
    const float* src = x + ((size_t)b * NNODE + v0 + vr) * 64 + c0;
    __bf16* xb = xbf + ((size_t)b * NNODE + v0 + vr) * 64 + c0;
#pragma unroll
    for (int j = 0; j < 4; ++j) {
      float4 q = ((const float4*)src)[j];
      t[vr][c0 + j * 4 + 0] = q.x;
      t[vr][c0 + j * 4 + 1] = q.y;
      t[vr][c0 + j * 4 + 2] = q.z;
      t[vr][c0 + j * 4 + 3] = q.w;
      xb[j * 4 + 0] = (__bf16)q.x;
      xb[j * 4 + 1] = (__bf16)q.y;
      xb[j * 4 + 2] = (__bf16)q.z;
      xb[j * 4 + 3] = (__bf16)q.w;
    }
    __syncthreads();
#pragma unroll
    for (int jr = 0; jr < 16; ++jr) {
      int c = jr * 4 + (tid >> 6);
      int v = tid & 63;
      XT[((size_t)b * 64 + c) * NNODE + v0 + v] = (__bf16)t[v][c];
    }
  }
}

// ---------------------------------------------------------------------------
// Fused adjacency prep (R13: fp8 outputs for the M2 build).
//   ADJ8[z][r][c]  = fp8(128 * A_z[r][c])
//   ADJT8[z][c][r] = fp8(128 * w_z * A_z[r][c])
//   M1[r][c] = bf16(sum_z w_z A_z[r][c])
__global__ __launch_bounds__(256) void prep_adj(const float* __restrict__ A1,
                                                const float* __restrict__ A2,
                                                const __bf16* __restrict__ ADJ,
                                                unsigned char* __restrict__ ADJ8,
                                                unsigned char* __restrict__ ADJT8,
                                                __bf16* __restrict__ M1,
                                                const float* __restrict__ wpre,
                                                const float* __restrict__ wadp) {
  const int r0 = blockIdx.x * 64, c0 = blockIdx.y * 64;
  const int tid = threadIdx.x;
  const size_t NN2 = (size_t)NNODE * NNODE;
  const float wp = *wpre, wa = *wadp * 0.25f;
  const float SA = 128.f;
  __shared__ float t[64][65];
  const int vr = tid >> 2, cg = (tid & 3) * 16;
  float m1acc[16] = {};

  for (int z = 0; z < 6; ++z) {
    const float wz = (z < 2) ? wp : wa;
    float vv[16];
    if (z < 2) {
      const float* src = (z == 0 ? A1 : A2) + (size_t)(r0 + vr) * NNODE + c0 + cg;
#pragma unroll
      for (int j = 0; j < 4; ++j) {
        float4 q = ((const float4*)src)[j];
        vv[j * 4 + 0] = q.x; vv[j * 4 + 1] = q.y;
        vv[j * 4 + 2] = q.z; vv[j * 4 + 3] = q.w;
      }
    } else {
      const __bf16* p = ADJ + (size_t)(z - 2) * NN2 + (size_t)(r0 + vr) * NNODE + c0 + cg;
      bf16x8 q0 = ((const bf16x8*)p)[0];
      bf16x8 q1 = ((const bf16x8*)p)[1];
#pragma unroll
      for (int i = 0; i < 8; ++i) { vv[i] = (float)q0[i]; vv[8 + i] = (float)q1[i]; }
    }
#pragma unroll
    for (int i = 0; i < 16; ++i) {
      m1acc[i] += wz * vv[i];
      t[vr][cg + i] = vv[i];
    }
    // A-side fp8 (x128), row-major, int4 = 16 bytes
    {
      int4 pk;
#pragma unroll
      for (int q = 0; q < 4; ++q) {
        int w0 = __builtin_amdgcn_cvt_pk_fp8_f32(vv[4 * q] * SA, vv[4 * q + 1] * SA, 0, false);
        w0 = __builtin_amdgcn_cvt_pk_fp8_f32(vv[4 * q + 2] * SA, vv[4 * q + 3] * SA, w0, true);
        (&pk.x)[q] = w0;
      }
      *(int4*)(ADJ8 + (size_t)z * NN2 + (size_t)(r0 + vr) * NNODE + c0 + cg) = pk;
    }
    __syncthreads();
    // B-side fp8 (x wz x128), transposed: ADJT8[c0+c][r0+v]
    {
      const float sb = wz * SA;
#pragma unroll
      for (int jr = 0; jr < 4; ++jr) {
        int c = jr * 16 + (tid >> 4);
        int vq = (tid & 15) * 4;
        int w0 = __builtin_amdgcn_cvt_pk_fp8_f32(t[vq][c] * sb, t[vq + 1][c] * sb, 0, false);
        w0 = __builtin_amdgcn_cvt_pk_fp8_f32(t[vq + 2][c] * sb, t[vq + 3][c] * sb, w0, true);
        *(int*)(ADJT8 + (size_t)z * NN2 + (size_t)(c0 + c) * NNODE + r0 + vq) = w0;
      }
    }
    __syncthreads();
  }
  __bf16* q = M1 + (size_t)(r0 + vr) * NNODE + c0 + cg;
  bf16x8 o0, o1;
#pragma unroll
  for (int i = 0; i < 8; ++i) { o0[i] = (__bf16)m1acc[i]; o1[i] = (__bf16)m1acc[8 + i]; }
  ((bf16x8*)q)[0] = o0;
  ((bf16x8*)q)[1] = o1;
}

// ---------------------------------------------------------------------------
// Sync macros (shared).
#define VMCNT0() asm volatile("s_waitcnt vmcnt(0)" ::: "memory")
#define VMCNT4() asm volatile("s_waitcnt vmcnt(4)" ::: "memory")
#define VMCNT8() asm volatile("s_waitcnt vmcnt(8)" ::: "memory")
#define LGKMCNT0() asm volatile("s_waitcnt lgkmcnt(0)" ::: "memory")
#define BARRIER() asm volatile("s_barrier" ::: "memory")

// bf16 frag helpers (R11-verified, used by gemm_hop1s)
#define READFRAGS(d, AF, BF)                                                  \
  do {                                                                        \
    _Pragma("unroll")                                                         \
    for (int mi = 0; mi < 4; ++mi) {                                          \
      AF[mi][0] = *(const bf16x8*)(AREG(d) + aoff[mi][0]);                    \
      AF[mi][1] = *(const bf16x8*)(AREG(d) + aoff[mi][1]);                    \
    }                                                                         \
    _Pragma("unroll")                                                         \
    for (int j = 0; j < 4; ++j) {                                             \
      BF[j][0] = *(const bf16x8*)(BREG(d) + boff[j][0]);                      \
      BF[j][1] = *(const bf16x8*)(BREG(d) + boff[j][1]);                      \
    }                                                                         \
  } while (0)

#define MFMA16(AF, BF)                                                        \
  do {                                                                        \
    __builtin_amdgcn_s_setprio(1);                                            \
    _Pragma("unroll")                                                         \
    for (int mi = 0; mi < 4; ++mi)                                            \
      _Pragma("unroll")                                                       \
      for (int j = 0; j < 4; ++j)                                             \
        _Pragma("unroll")                                                     \
        for (int ks = 0; ks < 2; ++ks)                                        \
          acc[mi][j] = __builtin_amdgcn_mfma_f32_16x16x32_bf16(               \
              AF[mi][ks], BF[j][ks], acc[mi][j], 0, 0, 0);                    \
    __builtin_amdgcn_s_setprio(0);                                            \
  } while (0)

// fp8 frag helpers (gemm_sq)
#define READFRAGS8(d, AF, BF)                                                 \
  do {                                                                        \
    _Pragma("unroll")                                                         \
    for (int mi = 0; mi < 4; ++mi) {                                          \
      AF[mi][0] = *(const long*)(AREG8(d) + aoff[mi][0]);                     \
      AF[mi][1] = *(const long*)(AREG8(d) + aoff[mi][1]);                     \
    }                                                                         \
    _Pragma("unroll")                                                         \
    for (int j = 0; j < 4; ++j) {                                             \
      BF[j][0] = *(const long*)(BREG8(d) + boff[j][0]);                       \
      BF[j][1] = *(const long*)(BREG8(d) + boff[j][1]);                       \
    }                                                                         \
  } while (0)

#define MFMA8(AF, BF)                                                         \
  do {                                                                        \
    __builtin_amdgcn_s_setprio(1);                                            \
    _Pragma("unroll")                                                         \
    for (int mi = 0; mi < 4; ++mi)                                            \
      _Pragma("unroll")                                                       \
      for (int j = 0; j < 4; ++j)                                             \
        _Pragma("unroll")                                                     \
        for (int ks = 0; ks < 2; ++ks)                                        \
          acc[mi][j] = __builtin_amdgcn_mfma_f32_16x16x32_fp8_fp8(            \
              AF[mi][ks], BF[j][ks], acc[mi][j], 0, 0, 0);                    \
    __builtin_amdgcn_s_setprio(0);                                            \
  } while (0)

// ---------------------------------------------------------------------------
// Fused-squares (fp8): M2part[zh] = (1/16384) sum_{z in half} ADJ8_z @ ADJT8_z^T.
// 96 K-tiles/block, LDS 32 KiB -> 3 blocks/CU. 16B-granular XOR swizzle
// (byte ^= (row&6)<<3), inverse-staged global source. R11 pipeline, vmcnt(4).
__global__ __launch_bounds__(256, 3) void gemm_sq(const unsigned char* __restrict__ ADJ8,
                                                  const unsigned char* __restrict__ ADJT8,
                                                  float* __restrict__ M2part) {
  extern __shared__ char smem[];  // 32768 B
  const int tid = threadIdx.x;
  const int w = tid >> 6, l = tid & 63;
  const int wr = w >> 1, wc = w & 1;
  const size_t NN2 = (size_t)NNODE * NNODE;  // bytes per fp8 slice
  int lin = blockIdx.x + 16 * blockIdx.y + 256 * blockIdx.z;
  int nlin = (lin & 7) * 64 + (lin >> 3);
  const int m0 = (nlin & 15) * 128, n0 = ((nlin >> 4) & 15) * 128;
  const int zh = nlin >> 8;
  const int zb = zh * 3;
  float* Cp = M2part + (size_t)zh * NN2;
  const int NTT = 96;  // 3 z * 32 K-tiles (BK=64)

#define AREG8(d) (smem + (d) * 8192)
#define BREG8(d) (smem + 16384 + (d) * 8192)

  // swizzled read offsets within an 8 KiB region ([128 rows][64 B])
  int aoff[4][2], boff[4][2];
#pragma unroll
  for (int mi = 0; mi < 4; ++mi)
#pragma unroll
    for (int ks = 0; ks < 2; ++ks) {
      int rh = mi * 32 + wr * 16 + (l & 15);
      int lo = rh * 64 + ks * 32 + ((l >> 4) * 8);
      aoff[mi][ks] = lo ^ ((rh & 6) << 3);
    }
#pragma unroll
  for (int j = 0; j < 4; ++j)
#pragma unroll
    for (int ks = 0; ks < 2; ++ks) {
      int rh = j * 32 + wc * 16 + (l & 15);
      int lo = rh * 64 + ks * 32 + ((l >> 4) * 8);
      boff[j][ks] = lo ^ ((rh & 6) << 3);
    }

  // staging: LDS dest linear (o = p*4096 + w*1024 + l*16, row = p*64+w*16+(l>>2));
  // global source 16B-unit index XORed with (row>>1)&3 = (l>>3)&3.
  const int sg_col = (((l & 3) ^ ((l >> 3) & 3)) << 4);
  unsigned aLoff[2], bLoff[2];
#pragma unroll
  for (int p = 0; p < 2; ++p) {
    int srow = p * 64 + w * 16 + (l >> 2);
    aLoff[p] = (unsigned)((m0 + srow) * 2048 + sg_col);
    bLoff[p] = (unsigned)((n0 + srow) * 2048 + sg_col);
  }

#define STAGE8A(toff, region)                                                 \
  do {                                                                        \
    _Pragma("unroll")                                                         \
    for (int p = 0; p < 2; ++p)                                               \
      gload16((const char*)ADJ8 + (toff) + aLoff[p],                          \
              (region) + p * 4096 + w * 1024);                                \
  } while (0)
#define STAGE8B(toff, region)                                                 \
  do {                                                                        \
    _Pragma("unroll")                                                         \
    for (int p = 0; p < 2; ++p)                                               \
      gload16((const char*)ADJT8 + (toff) + bLoff[p],                         \
              (region) + p * 4096 + w * 1024);                                \
  } while (0)

  f32x4 acc[4][4] = {};
  long afA[4][2], bfA[4][2], afB[4][2], bfB[4][2];

  // prologue: tiles 0,1 staged (4 loads each); frags(0) read into A-set
  size_t tOff = (size_t)zb * NN2;
  STAGE8A(tOff, AREG8(0));
  STAGE8B(tOff, BREG8(0));
  STAGE8A(tOff + 64, AREG8(1));
  STAGE8B(tOff + 64, BREG8(1));
  tOff += 128;
  VMCNT4();   // tile0 landed (tile1's 4 in flight)
  BARRIER();
  READFRAGS8(0, afA, bfA);
  LGKMCNT0();
  BARRIER();

  for (int t = 0; t <= NTT - 4; t += 2) {
    STAGE8A(tOff, AREG8(0));
    STAGE8B(tOff, BREG8(0));
    tOff += (((t + 2) & 31) == 31) ? (NN2 - (size_t)31 * 64) : (size_t)64;
    VMCNT4();
    BARRIER();
    READFRAGS8(1, afB, bfB);
    MFMA8(afA, bfA);
    LGKMCNT0();
    BARRIER();
    STAGE8A(tOff, AREG8(1));
    STAGE8B(tOff, BREG8(1));
    tOff += (((t + 3) & 31) == 31) ? (NN2 - (size_t)31 * 64) : (size_t)64;
    VMCNT4();
    BARRIER();
    READFRAGS8(0, afA, bfA);
    MFMA8(afB, bfB);
    LGKMCNT0();
    BARRIER();
  }
  VMCNT0();
  BARRIER();
  READFRAGS8(1, afB, bfB);
  MFMA8(afA, bfA);
  LGKMCNT0();
  MFMA8(afB, bfB);

  const float DS = 1.f / 16384.f;  // 1/(SA*SA)
  const int crow = (l >> 4) * 4;
  const int ccol = l & 15;
#pragma unroll
  for (int mi = 0; mi < 4; ++mi)
#pragma unroll
    for (int j = 0; j < 4; ++j) {
      int r0 = m0 + mi * 32 + wr * 16 + crow;
      int cc = n0 + j * 32 + wc * 16 + ccol;
#pragma unroll
      for (int r = 0; r < 4; ++r)
        Cp[(size_t)(r0 + r) * NNODE + cc] = acc[mi][j][r] * DS;
    }
#undef STAGE8A
#undef STAGE8B
#undef AREG8
#undef BREG8
}

// ---------------------------------------------------------------------------
// Stage GEMM with fused transposed epilogue (R9/R11-verified).
__global__ __launch_bounds__(256, 2) void gemm_hop1s(const __bf16* __restrict__ XT,
                                                     const __bf16* __restrict__ MMb,
                                                     __bf16* __restrict__ S1,
                                                     __bf16* __restrict__ S2) {
  extern __shared__ char smem[];  // 65536 B
  const int tid = threadIdx.x;
  const int w = tid >> 6, l = tid & 63;
  const int wr = w >> 1, wc = w & 1;
  const size_t NN2 = (size_t)NNODE * NNODE;
  int lin = blockIdx.x + 16 * blockIdx.y + 256 * blockIdx.z;
  int nlin = (lin & 7) * 64 + (lin >> 3);
  const int m0 = (nlin & 15) * 128, n0 = ((nlin >> 4) & 15) * 128;
  const int z = nlin >> 8;
  const char* Abase = (const char*)XT;
  const char* Bbase = (const char*)(MMb + (size_t)z * NN2);
  const int NT = NNODE / 64;  // 32

#define AREG(d) (smem + (d) * 16384)
#define BREG(d) (smem + 32768 + (d) * 16384)

  int aoff[4][2], boff[4][2];
#pragma unroll
  for (int mi = 0; mi < 4; ++mi)
#pragma unroll
    for (int ks = 0; ks < 2; ++ks) {
      int rh = mi * 32 + wr * 16 + (l & 15);
      int lo = rh * 128 + ks * 64 + ((l >> 4) * 16);
      aoff[mi][ks] = lo ^ ((rh & 7) << 4);
    }
#pragma unroll
  for (int j = 0; j < 4; ++j)
#pragma unroll
    for (int ks = 0; ks < 2; ++ks) {
      int rh = j * 32 + wc * 16 + (l & 15);
      int lo = rh * 128 + ks * 64 + ((l >> 4) * 16);
      boff[j][ks] = lo ^ ((rh & 7) << 4);
    }

  const int sg_row = w * 8 + (l >> 3);
  const int sg_col = (((l & 7) ^ ((l >> 3) & 7)) << 4);
  unsigned aLoff[4], bLoff[4];
#pragma unroll
  for (int p = 0; p < 4; ++p) {
    aLoff[p] = (unsigned)((m0 + p * 32 + sg_row) * 4096 + sg_col);
    bLoff[p] = (unsigned)((n0 + p * 32 + sg_row) * 4096 + sg_col);
  }

#define STAGEA(koff, region)                                                  \
  do {                                                                        \
    _Pragma("unroll")                                                         \
    for (int p = 0; p < 4; ++p)                                               \
      gload16(Abase + (koff) + aLoff[p], (region) + p * 4096 + w * 1024);     \
  } while (0)
#define STAGEB(koff, region)                                                  \
  do {                                                                        \
    _Pragma("unroll")                                                         \
    for (int p = 0; p < 4; ++p)                                               \
      gload16(Bbase + (koff) + bLoff[p], (region) + p * 4096 + w * 1024);     \
  } while (0)

  f32x4 acc[4][4] = {};
  bf16x8 afA[4][2], bfA[4][2], afB[4][2], bfB[4][2];

  size_t kOff = 0;
  STAGEA(kOff, AREG(0));
  STAGEB(kOff, BREG(0));
  STAGEA(kOff + 128, AREG(1));
  STAGEB(kOff + 128, BREG(1));
  kOff += 256;
  VMCNT8();
  BARRIER();
  READFRAGS(0, afA, bfA);
  LGKMCNT0();
  BARRIER();

  for (int t = 0; t <= NT - 4; t += 2) {
    STAGEA(kOff, AREG(0));
    STAGEB(kOff, BREG(0));
    kOff += 128;
    VMCNT8();
    BARRIER();
    READFRAGS(1, afB, bfB);
    MFMA16(afA, bfA);
    LGKMCNT0();
    BARRIER();
    STAGEA(kOff, AREG(1));
    STAGEB(kOff, BREG(1));
    kOff += 128;
    VMCNT8();
    BARRIER();
    READFRAGS(0, afA, bfA);
    MFMA16(afB, bfB);
    LGKMCNT0();
    BARRIER();
  }
  VMCNT0();
  BARRIER();
  READFRAGS(1, afB, bfB);
  MFMA16(afA, bfA);
  LGKMCNT0();
  MFMA16(afB, bfB);

  // ---- epilogue: LDS transpose T[n][m] with slot-XOR swizzle, coalesced
  // write S_z[(b, n0+n)*64 + c].
  {
    __syncthreads();
    const int crow = (l >> 4) * 4;
    const int ccol = l & 15;
    char* T = smem;  // 128 x 256 B
#pragma unroll
    for (int mi = 0; mi < 4; ++mi)
#pragma unroll
      for (int j = 0; j < 4; ++j) {
        int ml = mi * 32 + wr * 16 + crow;
        int nl = j * 32 + wc * 16 + ccol;
        bf16x4 v;
#pragma unroll
        for (int r = 0; r < 4; ++r) v[r] = (__bf16)acc[mi][j][r];
        *(bf16x4*)(T + nl * 256 + ((ml * 2) ^ ((nl & 7) << 4))) = v;
      }
    __syncthreads();
    __bf16* dst = z ? S2 : S1;
    const int bA = m0 >> 6;
#pragma unroll
    for (int it = 0; it < 4; ++it) {
      int nl = (tid >> 3) + it * 32;
      int seg = tid & 7;
      int xorv = (nl & 7) << 4;
      const char* src = T + nl * 256;
      bf16x8 v0 = *(const bf16x8*)(src + ((seg * 32) ^ xorv));
      bf16x8 v1 = *(const bf16x8*)(src + ((seg * 32 + 16) ^ xorv));
      int b = bA + (seg >> 2);
      size_t o = ((size_t)b * NNODE + n0 + nl) * 64 + (seg & 3) * 16;
      *(bf16x8*)(dst + o) = v0;
      *(bf16x8*)(dst + o + 8) = v1;
    }
  }
#undef STAGEA
#undef STAGEB
#undef AREG
#undef BREG
}

// ---------------------------------------------------------------------------
// M2[i] = (bf16)(M2a[i] + M2b[i])
__global__ __launch_bounds__(256) void combine_m2(const float* __restrict__ M2p,
                                                  __bf16* __restrict__ M2) {
  const size_t NN2 = (size_t)NNODE * NNODE;
  size_t i = ((size_t)blockIdx.x * 256 + threadIdx.x) * 4;
  float4 a = *(const float4*)(M2p + i);
  float4 b = *(const float4*)(M2p + NN2 + i);
  M2[i + 0] = (__bf16)(a.x + b.x);
  M2[i + 1] = (__bf16)(a.y + b.y);
  M2[i + 2] = (__bf16)(a.z + b.z);
  M2[i + 3] = (__bf16)(a.w + b.w);
}

// ---------------------------------------------------------------------------
// Gate linear GEMM: [65536 x 192] @ Wt^T, K=192, N=128, fused epilogues.
// MODE 0: cols 0-63 -> z=sigmoid -> zbuf(f32); cols 64-127 -> r ->
//         rx=(bf16)(r*hid) row-major AND rxT -> XTout via LDS transpose.
// MODE 1: cols 0-63 -> c=tanh -> out=(1-z)*hid+z*c (f32)
template <int MODE>
__global__ __launch_bounds__(256) void gemm_lin(const __bf16* __restrict__ Xp,
                                                const __bf16* __restrict__ S1,
                                                const __bf16* __restrict__ S2,
                                                const __bf16* __restrict__ Wt,
                                                const float* __restrict__ b0,
                                                const float* __restrict__ b1,
                                                const float* __restrict__ wpre,
                                                const float* __restrict__ wadp,
                                                const float* __restrict__ hid,
                                                float* __restrict__ zbuf,
                                                __bf16* __restrict__ rxout,
                                                __bf16* __restrict__ XTout,
                                                float* __restrict__ outp) {
  __shared__ __bf16 As[128 * 32];
  __shared__ __bf16 Bs[128 * 32];
  __shared__ char T[64 * 256];  // rx transpose staging (MODE 0)
  const int tid = threadIdx.x;
  const int wave = tid >> 6, lane = tid & 63;
  const int wr = wave >> 1, wc = wave & 1;
  const int m0 = blockIdx.x * 128;
  const int rowA = tid >> 2;
  const int colb = (tid & 3) * 16;
  const __bf16* srcs[3] = {Xp, S1, S2};
  char* asD0 = (char*)As + wave * 1024;
  char* asD1 = (char*)As + 4096 + wave * 1024;
  char* bsD0 = (char*)Bs + wave * 1024;
  char* bsD1 = (char*)Bs + 4096 + wave * 1024;

  f32x4 acc[4][4] = {};

#pragma unroll
  for (int kt = 0; kt < 6; ++kt) {
    const __bf16* Ab = srcs[kt >> 1];
    const char* aS0 = (const char*)(Ab + (size_t)(m0 + rowA) * 64) + (kt & 1) * 64 + colb;
    const char* aS1 = (const char*)(Ab + (size_t)(m0 + rowA + 64) * 64) + (kt & 1) * 64 + colb;
    const char* bS0 = (const char*)(Wt + (size_t)rowA * 192) + kt * 64 + colb;
    const char* bS1 = (const char*)(Wt + (size_t)(rowA + 64) * 192) + kt * 64 + colb;
    gload16(aS0, asD0);
    gload16(aS1, asD1);
    gload16(bS0, bsD0);
    gload16(bS1, bsD1);
    __syncthreads();
    bf16x8 af[4], bfr[4];
#pragma unroll
    for (int mi = 0; mi < 4; ++mi)
      af[mi] = *(const bf16x8*)((const char*)As +
               ((wr * 64 + mi * 16 + (lane & 15)) * 64 + (lane >> 4) * 16));
#pragma unroll
    for (int ni = 0; ni < 4; ++ni)
      bfr[ni] = *(const bf16x8*)((const char*)Bs +
               ((wc * 64 + ni * 16 + (lane & 15)) * 64 + (lane >> 4) * 16));
#pragma unroll
    for (int mi = 0; mi < 4; ++mi)
#pragma unroll
      for (int ni = 0; ni < 4; ++ni)
        acc[mi][ni] = __builtin_amdgcn_mfma_f32_16x16x32_bf16(af[mi], bfr[ni],
                                                              acc[mi][ni], 0, 0, 0);
    __syncthreads();
  }

  const float wp = *wpre, wa = *wadp;
  const float s = 2.f * wp + wa;
  const int crow = (lane >> 4) * 4;
  const int ccol = lane & 15;
#pragma unroll
  for (int mi = 0; mi < 4; ++mi)
#pragma unroll
    for (int ni = 0; ni < 4; ++ni) {
      int r0 = m0 + wr * 64 + mi * 16 + crow;
      int col = wc * 64 + ni * 16 + ccol;
      int cf = col & 63;
      if (MODE == 0) {
        if (col < 64) {
#pragma unroll
          for (int r = 0; r < 4; ++r) {
            int row = r0 + r;
            float g = acc[mi][ni][r] + s * b0[cf];
            zbuf[(size_t)row * 64 + cf] = 1.f / (1.f + __expf(-g));
          }
        } else {
          bf16x4 tv;
#pragma unroll
          for (int r = 0; r < 4; ++r) {
            int row = r0 + r;
            float g = acc[mi][ni][r] + s * b1[cf];
            float rv = 1.f / (1.f + __expf(-g));
            __bf16 rxv = (__bf16)(rv * hid[(size_t)row * 64 + cf]);
            rxout[(size_t)row * 64 + cf] = rxv;
            tv[r] = rxv;
          }
          int vl0 = wr * 64 + mi * 16 + crow;
          *(bf16x4*)(T + cf * 256 + ((vl0 * 2) ^ ((cf & 7) << 4))) = tv;
        }
      } else {
        if (col < 64) {
#pragma unroll
          for (int r = 0; r < 4; ++r) {
            int row = r0 + r;
            float g = acc[mi][ni][r] + s * b0[cf];
            float cv = 1.f - 2.f / (1.f + __expf(2.f * g));
            float zv = zbuf[(size_t)row * 64 + cf];
            float hv = hid[(size_t)row * 64 + cf];
            outp[(size_t)row * 64 + cf] = (1.f - zv) * hv + zv * cv;
          }
        }
      }
    }

  if (MODE == 0) {
    __syncthreads();
    const int b = m0 >> 11;
    const int v0 = m0 & 2047;
#pragma unroll
    for (int it = 0; it < 4; ++it) {
      int rr = it * 16 + (tid >> 4);
      int seg = tid & 15;
      bf16x8 v = *(const bf16x8*)(T + rr * 256 + ((seg * 16) ^ ((rr & 7) << 4)));
      *(bf16x8*)(XTout + ((size_t)(b * 64 + rr)) * NNODE + v0 + seg * 8) = v;
    }
  }
}

// ---------------------------------------------------------------------------
extern "C" void kernel_launch(void* const* d_in, const int* in_sizes, int n_in,
                              void* d_out, int out_size, void* d_ws, size_t ws_size,
                              hipStream_t stream) {
  (void)in_sizes; (void)n_in; (void)out_size;
  const float* x    = (const float*)d_in[0];
  const float* A1   = (const float*)d_in[1];
  const float* A2   = (const float*)d_in[2];
  const float* E1   = (const float*)d_in[3];
  const float* E2   = (const float*)d_in[4];
  const float* Wz   = (const float*)d_in[5];
  const float* bz   = (const float*)d_in[6];
  const float* Wr   = (const float*)d_in[7];
  const float* br   = (const float*)d_in[8];
  const float* Wc   = (const float*)d_in[9];
  const float* bc   = (const float*)d_in[10];
  const float* wpre = (const float*)d_in[11];
  const float* wadp = (const float*)d_in[12];
  float* out = (float*)d_out;

  char* ws = (char*)d_ws;
  const size_t NN2 = (size_t)NNODE * NNODE;  // 4,194,304
  const size_t NN2B = NN2 * 2;               // bytes per bf16 slice
  __bf16* ADJ  = (__bf16*)(ws);                 // [0,6): slices 0..3 = softmax out (z=2..5)
  unsigned char* ADJ8  = (unsigned char*)(ws + 6 * NN2B);          // 6 fp8 slices
  unsigned char* ADJT8 = (unsigned char*)(ws + 6 * NN2B + 6 * NN2);// 6 fp8 slices
  __bf16* SC   = (__bf16*)(ws + 12 * NN2B);     // scores (4 slices), then:
  float*  M2p  = (float*)(ws + 12 * NN2B);      // f32 partials x2 = [12,16)
  __bf16* MM   = (__bf16*)(ws + 18 * NN2B);     // M1 @18, M2 @19
  __bf16* XT   = (__bf16*)(ws + 20 * NN2B);
  __bf16* xbf  = (__bf16*)(ws + 21 * NN2B);
  __bf16* rx   = (__bf16*)(ws + 22 * NN2B);
  __bf16* S1   = (__bf16*)(ws + 2 * NN2B);      // over ADJ slice 2 (dead post-prep)
  __bf16* S2   = (__bf16*)(ws + 3 * NN2B);      // over ADJ slice 3
  float*  zbuf = (float*)(ws + 4 * NN2B);       // over ADJ slices 4..5
  __bf16* E1p  = (__bf16*)(ws + 23 * NN2B);
  __bf16* E2p  = E1p + 4 * NNODE * 32;
  __bf16* Wzrt = E2p + 4 * NNODE * 32;
  __bf16* Wct  = Wzrt + 128 * 192;
  if (ws_size < 23 * NN2B + 2 * 4 * NNODE * 32 * 2 + 2 * 128 * 192 * 2) return;

  // --- adjacency construction (fused)
  prep_ew<<<224, 256, 0, stream>>>(E1, E2, Wz, Wr, Wc, wpre, wadp,
                                   E1p, E2p, Wzrt, Wct);
  score_gemm<<<dim3(16, 16, 4), 256, 0, stream>>>(E1p, E2p, SC);
  soft_tx<<<3072, 256, 0, stream>>>(SC, ADJ, x, XT, xbf);  // softmax out @ slices 0..3
  prep_adj<<<dim3(32, 32), 256, 0, stream>>>(A1, A2, ADJ + 2 * NN2 - 2 * NN2,
                                             ADJ8, ADJT8, MM, wpre, wadp);

  // --- M2 = sum_z w_z A_z^2 (fp8 fused accumulate; 512 blocks, XCD-chunked)
  gemm_sq<<<dim3(16, 16, 2), 256, 32768, stream>>>(ADJ8, ADJT8, M2p);
  combine_m2<<<4096, 256, 0, stream>>>(M2p, MM + NN2);

  // --- stage 1: S1 = M1 x, S2 = M2 x (fused transposed epilogue)
  gemm_hop1s<<<dim3(16, 16, 2), 256, 65536, stream>>>(XT, MM, S1, S2);
  gemm_lin<0><<<512, 256, 0, stream>>>(xbf, S1, S2, Wzrt, bz, br, wpre, wadp,
                                       x, zbuf, rx, XT, nullptr);

  // --- stage 2: hops on r*x (XT already holds rx^T from gemm_lin<0>)
  gemm_hop1s<<<dim3(16, 16, 2), 256, 65536, stream>>>(XT, MM, S1, S2);
  gemm_lin<1><<<512, 256, 0, stream>>>(rx, S1, S2, Wct, bc, nullptr, wpre, wadp,
                                       x, zbuf, nullptr, nullptr, out);
}

// Round 14
// 209.606 us; speedup vs baseline: 1.3043x; 1.0933x over previous
//
#include <hip/hip_runtime.h>

#define NNODE 2048
#define NBATCH 32

typedef __attribute__((ext_vector_type(4))) float f32x4;
typedef __attribute__((ext_vector_type(8))) __bf16 bf16x8;
typedef __attribute__((ext_vector_type(4))) __bf16 bf16x4;

__device__ __forceinline__ void gload16(const void* g, void* lds) {
  __builtin_amdgcn_global_load_lds(
      (const __attribute__((address_space(1))) unsigned int*)g,
      (__attribute__((address_space(3))) unsigned int*)lds, 16, 0, 0);
}

// ---------------------------------------------------------------------------
// Merged: prep_e (blocks 0..127) + prep_w (blocks 128..223)
__global__ __launch_bounds__(256) void prep_ew(const float* __restrict__ E1,
                                               const float* __restrict__ E2,
                                               const float* __restrict__ Wz,
                                               const float* __restrict__ Wr,
                                               const float* __restrict__ Wc,
                                               const float* __restrict__ wpre,
                                               const float* __restrict__ wadp,
                                               __bf16* __restrict__ E1p,
                                               __bf16* __restrict__ E2p,
                                               __bf16* __restrict__ Wzrt,
                                               __bf16* __restrict__ Wct) {
  if (blockIdx.x < 128) {
    int idx = blockIdx.x * 256 + threadIdx.x;  // 0..32767
    int cq = idx & 3;
    int n = (idx >> 2) & 2047;
    int h = idx >> 13;
    const float4 q1 = *(const float4*)(E1 + (size_t)(n * 4 + h) * 16 + cq * 4);
    const float4 q2 = *(const float4*)(E2 + (size_t)(n * 4 + h) * 16 + cq * 4);
    size_t o = ((size_t)h * NNODE + n) * 32 + cq * 4;
    E1p[o + 0] = (__bf16)q1.x; E1p[o + 1] = (__bf16)q1.y;
    E1p[o + 2] = (__bf16)q1.z; E1p[o + 3] = (__bf16)q1.w;
    E2p[o + 0] = (__bf16)q2.x; E2p[o + 1] = (__bf16)q2.y;
    E2p[o + 2] = (__bf16)q2.z; E2p[o + 3] = (__bf16)q2.w;
    size_t oz = o + 16;
    E1p[oz + 0] = (__bf16)0.f; E1p[oz + 1] = (__bf16)0.f;
    E1p[oz + 2] = (__bf16)0.f; E1p[oz + 3] = (__bf16)0.f;
    E2p[oz + 0] = (__bf16)0.f; E2p[oz + 1] = (__bf16)0.f;
    E2p[oz + 2] = (__bf16)0.f; E2p[oz + 3] = (__bf16)0.f;
  } else {
    int idx = (blockIdx.x - 128) * 256 + threadIdx.x;  // 0 .. 128*192-1
    int rr = idx / 192, k = idx % 192;
    float s = 2.f * (*wpre) + (*wadp);
    float sc = (k < 64) ? s : 1.f;
    float vz = (rr < 64) ? Wz[(size_t)k * 64 + rr] : Wr[(size_t)k * 64 + rr - 64];
    Wzrt[idx] = (__bf16)(vz * sc);
    float vc = (rr < 64) ? Wc[(size_t)k * 64 + rr] * sc : 0.f;
    Wct[idx] = (__bf16)vc;
  }
}

// ---------------------------------------------------------------------------
// SC[h][w][v] = relu(E1p_h @ E2p_h^T)/4, bf16. Single K=32 MFMA step.
__global__ __launch_bounds__(256) void score_gemm(const __bf16* __restrict__ E1p,
                                                  const __bf16* __restrict__ E2p,
                                                  __bf16* __restrict__ SC) {
  __shared__ __bf16 As[128 * 32];
  __shared__ __bf16 Bs[128 * 32];
  const int tid = threadIdx.x;
  const int wave = tid >> 6, lane = tid & 63;
  const int wr = wave >> 1, wc = wave & 1;
  const int h = blockIdx.z;
  const int m0 = blockIdx.x * 128, n0 = blockIdx.y * 128;
  const __bf16* A = E1p + (size_t)h * NNODE * 32;
  const __bf16* Bt = E2p + (size_t)h * NNODE * 32;
  const int rowA = tid >> 2;
  const int colb = (tid & 3) * 16;
  gload16((const char*)(A + (size_t)(m0 + rowA) * 32) + colb, (char*)As + wave * 1024);
  gload16((const char*)(A + (size_t)(m0 + rowA + 64) * 32) + colb, (char*)As + 4096 + wave * 1024);
  gload16((const char*)(Bt + (size_t)(n0 + rowA) * 32) + colb, (char*)Bs + wave * 1024);
  gload16((const char*)(Bt + (size_t)(n0 + rowA + 64) * 32) + colb, (char*)Bs + 4096 + wave * 1024);
  __syncthreads();

  f32x4 acc[4][4] = {};
  bf16x8 af[4], bfr[4];
#pragma unroll
  for (int mi = 0; mi < 4; ++mi)
    af[mi] = *(const bf16x8*)((const char*)As +
             ((wr * 64 + mi * 16 + (lane & 15)) * 64 + (lane >> 4) * 16));
#pragma unroll
  for (int ni = 0; ni < 4; ++ni)
    bfr[ni] = *(const bf16x8*)((const char*)Bs +
             ((wc * 64 + ni * 16 + (lane & 15)) * 64 + (lane >> 4) * 16));
#pragma unroll
  for (int mi = 0; mi < 4; ++mi)
#pragma unroll
    for (int ni = 0; ni < 4; ++ni)
      acc[mi][ni] = __builtin_amdgcn_mfma_f32_16x16x32_bf16(af[mi], bfr[ni],
                                                            acc[mi][ni], 0, 0, 0);

  const int crow = (lane >> 4) * 4;
  const int ccol = lane & 15;
#pragma unroll
  for (int mi = 0; mi < 4; ++mi)
#pragma unroll
    for (int ni = 0; ni < 4; ++ni) {
      int r0 = m0 + wr * 64 + mi * 16 + crow;
      int cc = n0 + wc * 64 + ni * 16 + ccol;
#pragma unroll
      for (int r = 0; r < 4; ++r) {
        float val = fmaxf(acc[mi][ni][r], 0.f) * 0.25f;
        SC[((size_t)h * NNODE + r0 + r) * NNODE + cc] = (__bf16)val;
      }
    }
}

// ---------------------------------------------------------------------------
// Merged: blocks 0..2047 -> row softmax (SC -> adjh); blocks 2048..3071 ->
// transpose_x: x f32 -> XT8 fp8(16x) [B*64,N] and xbf bf16 [B*N,64].
__global__ __launch_bounds__(256) void soft_tx(const __bf16* __restrict__ SC,
                                               __bf16* __restrict__ adjh,
                                               const float* __restrict__ x,
                                               unsigned char* __restrict__ XT8,
                                               __bf16* __restrict__ xbf) {
  const int tid = threadIdx.x;
  if (blockIdx.x < 2048) {
    const int wave = tid >> 6, lane = tid & 63;
    const size_t row = (size_t)blockIdx.x * 4 + wave;
    const __bf16* src = SC + row * NNODE;
    __bf16* dst = adjh + row * NNODE;
    float v[32];
    float mx = 0.f;
#pragma unroll
    for (int j = 0; j < 4; ++j) {
      bf16x8 q = *(const bf16x8*)(src + j * 512 + lane * 8);
#pragma unroll
      for (int i = 0; i < 8; ++i) {
        float f = (float)q[i];
        v[j * 8 + i] = f;
        mx = fmaxf(mx, f);
      }
    }
#pragma unroll
    for (int o = 32; o > 0; o >>= 1) mx = fmaxf(mx, __shfl_xor(mx, o));
    float s = 0.f;
#pragma unroll
    for (int i = 0; i < 32; ++i) {
      v[i] = __expf(v[i] - mx);
      s += v[i];
    }
#pragma unroll
    for (int o = 32; o > 0; o >>= 1) s += __shfl_xor(s, o);
    float inv = 1.f / s;
#pragma unroll
    for (int j = 0; j < 4; ++j) {
      bf16x8 q;
#pragma unroll
      for (int i = 0; i < 8; ++i) q[i] = (__bf16)(v[j * 8 + i] * inv);
      *(bf16x8*)(dst + j * 512 + lane * 8) = q;
    }
  } else {
    const int idx = blockIdx.x - 2048;
    const int b = idx >> 5, v0 = (idx & 31) * 64;
    __shared__ float t[64][65];
    const int vr = tid >> 2, c0 = (tid & 3) * 16;
    const float* src = x + ((size_t)b * NNODE + v0 + vr) * 64 + c0;
    __bf16* xb = xbf + ((size_t)b * NNODE + v0 + vr) * 64 + c0;
#pragma unroll
    for (int j = 0; j < 4; ++j) {
      float4 q = ((const float4*)src)[j];
      t[vr][c0 + j * 4 + 0] = q.x;
      t[vr][c0 + j * 4 + 1] = q.y;
      t[vr][c0 + j * 4 + 2] = q.z;
      t[vr][c0 + j * 4 + 3] = q.w;
      xb[j * 4 + 0] = (__bf16)q.x;
      xb[j * 4 + 1] = (__bf16)q.y;
      xb[j * 4 + 2] = (__bf16)q.z;
      xb[j * 4 + 3] = (__bf16)q.w;
    }
    __syncthreads();
    const float SX = 16.f;
#pragma unroll
    for (int jr = 0; jr < 4; ++jr) {
      int c = jr * 16 + (tid >> 4);
      int vq = (tid & 15) * 4;
      int w0 = __builtin_amdgcn_cvt_pk_fp8_f32(t[vq][c] * SX, t[vq + 1][c] * SX, 0, false);
      w0 = __builtin_amdgcn_cvt_pk_fp8_f32(t[vq + 2][c] * SX, t[vq + 3][c] * SX, w0, true);
      *(int*)(XT8 + ((size_t)(b * 64 + c)) * NNODE + v0 + vq) = w0;
    }
  }
}

// ---------------------------------------------------------------------------
// Fused adjacency prep (fp8 outputs): ADJ8 = fp8(128 A_z), ADJT8 =
// fp8(128 w_z A_z^T), M18 = fp8(128 sum_z w_z A_z).
__global__ __launch_bounds__(256) void prep_adj(const float* __restrict__ A1,
                                                const float* __restrict__ A2,
                                                const __bf16* __restrict__ ADJ,
                                                unsigned char* __restrict__ ADJ8,
                                                unsigned char* __restrict__ ADJT8,
                                                unsigned char* __restrict__ M18,
                                                const float* __restrict__ wpre,
                                                const float* __restrict__ wadp) {
  const int r0 = blockIdx.x * 64, c0 = blockIdx.y * 64;
  const int tid = threadIdx.x;
  const size_t NN2 = (size_t)NNODE * NNODE;
  const float wp = *wpre, wa = *wadp * 0.25f;
  const float SA = 128.f;
  __shared__ float t[64][65];
  const int vr = tid >> 2, cg = (tid & 3) * 16;
  float m1acc[16] = {};

  for (int z = 0; z < 6; ++z) {
    const float wz = (z < 2) ? wp : wa;
    float vv[16];
    if (z < 2) {
      const float* src = (z == 0 ? A1 : A2) + (size_t)(r0 + vr) * NNODE + c0 + cg;
#pragma unroll
      for (int j = 0; j < 4; ++j) {
        float4 q = ((const float4*)src)[j];
        vv[j * 4 + 0] = q.x; vv[j * 4 + 1] = q.y;
        vv[j * 4 + 2] = q.z; vv[j * 4 + 3] = q.w;
      }
    } else {
      const __bf16* p = ADJ + (size_t)(z - 2) * NN2 + (size_t)(r0 + vr) * NNODE + c0 + cg;
      bf16x8 q0 = ((const bf16x8*)p)[0];
      bf16x8 q1 = ((const bf16x8*)p)[1];
#pragma unroll
      for (int i = 0; i < 8; ++i) { vv[i] = (float)q0[i]; vv[8 + i] = (float)q1[i]; }
    }
#pragma unroll
    for (int i = 0; i < 16; ++i) {
      m1acc[i] += wz * vv[i];
      t[vr][cg + i] = vv[i];
    }
    {
      int4 pk;
#pragma unroll
      for (int q = 0; q < 4; ++q) {
        int w0 = __builtin_amdgcn_cvt_pk_fp8_f32(vv[4 * q] * SA, vv[4 * q + 1] * SA, 0, false);
        w0 = __builtin_amdgcn_cvt_pk_fp8_f32(vv[4 * q + 2] * SA, vv[4 * q + 3] * SA, w0, true);
        (&pk.x)[q] = w0;
      }
      *(int4*)(ADJ8 + (size_t)z * NN2 + (size_t)(r0 + vr) * NNODE + c0 + cg) = pk;
    }
    __syncthreads();
    {
      const float sb = wz * SA;
#pragma unroll
      for (int jr = 0; jr < 4; ++jr) {
        int c = jr * 16 + (tid >> 4);
        int vq = (tid & 15) * 4;
        int w0 = __builtin_amdgcn_cvt_pk_fp8_f32(t[vq][c] * sb, t[vq + 1][c] * sb, 0, false);
        w0 = __builtin_amdgcn_cvt_pk_fp8_f32(t[vq + 2][c] * sb, t[vq + 3][c] * sb, w0, true);
        *(int*)(ADJT8 + (size_t)z * NN2 + (size_t)(c0 + c) * NNODE + r0 + vq) = w0;
      }
    }
    __syncthreads();
  }
  {
    int4 pk;
#pragma unroll
    for (int q = 0; q < 4; ++q) {
      int w0 = __builtin_amdgcn_cvt_pk_fp8_f32(m1acc[4 * q] * SA, m1acc[4 * q + 1] * SA, 0, false);
      w0 = __builtin_amdgcn_cvt_pk_fp8_f32(m1acc[4 * q + 2] * SA, m1acc[4 * q + 3] * SA, w0, true);
      (&pk.x)[q] = w0;
    }
    *(int4*)(M18 + (size_t)(r0 + vr) * NNODE + c0 + cg) = pk;
  }
}

// ---------------------------------------------------------------------------
#define VMCNT0() asm volatile("s_waitcnt vmcnt(0)" ::: "memory")
#define VMCNT4() asm volatile("s_waitcnt vmcnt(4)" ::: "memory")
#define LGKMCNT0() asm volatile("s_waitcnt lgkmcnt(0)" ::: "memory")
#define BARRIER() asm volatile("s_barrier" ::: "memory")

// fp8 frag helpers
#define READFRAGS8(d, AF, BF)                                                 \
  do {                                                                        \
    _Pragma("unroll")                                                         \
    for (int mi = 0; mi < 4; ++mi) {                                          \
      AF[mi][0] = *(const long*)(AREG8(d) + aoff[mi][0]);                     \
      AF[mi][1] = *(const long*)(AREG8(d) + aoff[mi][1]);                     \
    }                                                                         \
    _Pragma("unroll")                                                         \
    for (int j = 0; j < 4; ++j) {                                             \
      BF[j][0] = *(const long*)(BREG8(d) + boff[j][0]);                       \
      BF[j][1] = *(const long*)(BREG8(d) + boff[j][1]);                       \
    }                                                                         \
  } while (0)

#define MFMA8(AF, BF)                                                         \
  do {                                                                        \
    __builtin_amdgcn_s_setprio(1);                                            \
    _Pragma("unroll")                                                         \
    for (int mi = 0; mi < 4; ++mi)                                            \
      _Pragma("unroll")                                                       \
      for (int j = 0; j < 4; ++j)                                             \
        _Pragma("unroll")                                                     \
        for (int ks = 0; ks < 2; ++ks)                                        \
          acc[mi][j] = __builtin_amdgcn_mfma_f32_16x16x32_fp8_fp8(            \
              AF[mi][ks], BF[j][ks], acc[mi][j], 0, 0, 0);                    \
    __builtin_amdgcn_s_setprio(0);                                            \
  } while (0)

// fp8 swizzle/staging geometry (R13-verified), shared by gemm_sq/gemm_hop1s8.
#define FP8_GEOM()                                                            \
  int aoff[4][2], boff[4][2];                                                 \
  _Pragma("unroll")                                                           \
  for (int mi = 0; mi < 4; ++mi)                                              \
    _Pragma("unroll")                                                         \
    for (int ks = 0; ks < 2; ++ks) {                                          \
      int rh = mi * 32 + wr * 16 + (l & 15);                                  \
      int lo = rh * 64 + ks * 32 + ((l >> 4) * 8);                            \
      aoff[mi][ks] = lo ^ ((rh & 6) << 3);                                    \
    }                                                                         \
  _Pragma("unroll")                                                           \
  for (int j = 0; j < 4; ++j)                                                 \
    _Pragma("unroll")                                                         \
    for (int ks = 0; ks < 2; ++ks) {                                          \
      int rh = j * 32 + wc * 16 + (l & 15);                                   \
      int lo = rh * 64 + ks * 32 + ((l >> 4) * 8);                            \
      boff[j][ks] = lo ^ ((rh & 6) << 3);                                     \
    }                                                                         \
  const int sg_col = (((l & 3) ^ ((l >> 3) & 3)) << 4);                       \
  unsigned aLoff[2], bLoff[2];                                                \
  _Pragma("unroll")                                                           \
  for (int p = 0; p < 2; ++p) {                                               \
    int srow = p * 64 + w * 16 + (l >> 2);                                    \
    aLoff[p] = (unsigned)((m0 + srow) * 2048 + sg_col);                       \
    bLoff[p] = (unsigned)((n0 + srow) * 2048 + sg_col);                       \
  }

// ---------------------------------------------------------------------------
// Fused-squares (fp8): M2part[zh] = (1/16384) sum_{z in half} ADJ8_z @ ADJT8_z^T.
__global__ __launch_bounds__(256, 3) void gemm_sq(const unsigned char* __restrict__ ADJ8,
                                                  const unsigned char* __restrict__ ADJT8,
                                                  float* __restrict__ M2part) {
  extern __shared__ char smem[];  // 32768 B
  const int tid = threadIdx.x;
  const int w = tid >> 6, l = tid & 63;
  const int wr = w >> 1, wc = w & 1;
  const size_t NN2 = (size_t)NNODE * NNODE;
  int lin = blockIdx.x + 16 * blockIdx.y + 256 * blockIdx.z;
  int nlin = (lin & 7) * 64 + (lin >> 3);
  const int m0 = (nlin & 15) * 128, n0 = ((nlin >> 4) & 15) * 128;
  const int zh = nlin >> 8;
  const int zb = zh * 3;
  float* Cp = M2part + (size_t)zh * NN2;
  const int NTT = 96;

#define AREG8(d) (smem + (d) * 8192)
#define BREG8(d) (smem + 16384 + (d) * 8192)

  FP8_GEOM();

#define STAGE8A(toff, region)                                                 \
  do {                                                                        \
    _Pragma("unroll")                                                         \
    for (int p = 0; p < 2; ++p)                                               \
      gload16((const char*)ADJ8 + (toff) + aLoff[p],                          \
              (region) + p * 4096 + w * 1024);                                \
  } while (0)
#define STAGE8B(toff, region)                                                 \
  do {                                                                        \
    _Pragma("unroll")                                                         \
    for (int p = 0; p < 2; ++p)                                               \
      gload16((const char*)ADJT8 + (toff) + bLoff[p],                         \
              (region) + p * 4096 + w * 1024);                                \
  } while (0)

  f32x4 acc[4][4] = {};
  long afA[4][2], bfA[4][2], afB[4][2], bfB[4][2];

  size_t tOff = (size_t)zb * NN2;
  STAGE8A(tOff, AREG8(0));
  STAGE8B(tOff, BREG8(0));
  STAGE8A(tOff + 64, AREG8(1));
  STAGE8B(tOff + 64, BREG8(1));
  tOff += 128;
  VMCNT4();
  BARRIER();
  READFRAGS8(0, afA, bfA);
  LGKMCNT0();
  BARRIER();

  for (int t = 0; t <= NTT - 4; t += 2) {
    STAGE8A(tOff, AREG8(0));
    STAGE8B(tOff, BREG8(0));
    tOff += (((t + 2) & 31) == 31) ? (NN2 - (size_t)31 * 64) : (size_t)64;
    VMCNT4();
    BARRIER();
    READFRAGS8(1, afB, bfB);
    MFMA8(afA, bfA);
    LGKMCNT0();
    BARRIER();
    STAGE8A(tOff, AREG8(1));
    STAGE8B(tOff, BREG8(1));
    tOff += (((t + 3) & 31) == 31) ? (NN2 - (size_t)31 * 64) : (size_t)64;
    VMCNT4();
    BARRIER();
    READFRAGS8(0, afA, bfA);
    MFMA8(afB, bfB);
    LGKMCNT0();
    BARRIER();
  }
  VMCNT0();
  BARRIER();
  READFRAGS8(1, afB, bfB);
  MFMA8(afA, bfA);
  LGKMCNT0();
  MFMA8(afB, bfB);

  const float DS = 1.f / 16384.f;
  const int crow = (l >> 4) * 4;
  const int ccol = l & 15;
#pragma unroll
  for (int mi = 0; mi < 4; ++mi)
#pragma unroll
    for (int j = 0; j < 4; ++j) {
      int r0 = m0 + mi * 32 + wr * 16 + crow;
      int cc = n0 + j * 32 + wc * 16 + ccol;
#pragma unroll
      for (int r = 0; r < 4; ++r)
        Cp[(size_t)(r0 + r) * NNODE + cc] = acc[mi][j][r] * DS;
    }
#undef STAGE8A
#undef STAGE8B
#undef AREG8
#undef BREG8
}

// ---------------------------------------------------------------------------
// fp8 stage GEMM with fused transposed epilogue:
//   S_z[(b,n),c] = (1/2048) sum_v XT8[(b,c)][v] * M_z8[n][v]
__global__ __launch_bounds__(256, 3) void gemm_hop1s8(const unsigned char* __restrict__ XT8,
                                                      const unsigned char* __restrict__ M18,
                                                      const unsigned char* __restrict__ M28,
                                                      __bf16* __restrict__ S1,
                                                      __bf16* __restrict__ S2) {
  extern __shared__ char smem[];  // 32768 B
  const int tid = threadIdx.x;
  const int w = tid >> 6, l = tid & 63;
  const int wr = w >> 1, wc = w & 1;
  int lin = blockIdx.x + 16 * blockIdx.y + 256 * blockIdx.z;
  int nlin = (lin & 7) * 64 + (lin >> 3);
  const int m0 = (nlin & 15) * 128, n0 = ((nlin >> 4) & 15) * 128;
  const int z = nlin >> 8;
  const unsigned char* Bbase = z ? M28 : M18;
  const int NT = NNODE / 64;  // 32

#define AREG8(d) (smem + (d) * 8192)
#define BREG8(d) (smem + 16384 + (d) * 8192)

  FP8_GEOM();

#define STAGE8A(koff, region)                                                 \
  do {                                                                        \
    _Pragma("unroll")                                                         \
    for (int p = 0; p < 2; ++p)                                               \
      gload16((const char*)XT8 + (koff) + aLoff[p],                           \
              (region) + p * 4096 + w * 1024);                                \
  } while (0)
#define STAGE8B(koff, region)                                                 \
  do {                                                                        \
    _Pragma("unroll")                                                         \
    for (int p = 0; p < 2; ++p)                                               \
      gload16((const char*)Bbase + (koff) + bLoff[p],                         \
              (region) + p * 4096 + w * 1024);                                \
  } while (0)

  f32x4 acc[4][4] = {};
  long afA[4][2], bfA[4][2], afB[4][2], bfB[4][2];

  size_t kOff = 0;
  STAGE8A(kOff, AREG8(0));
  STAGE8B(kOff, BREG8(0));
  STAGE8A(kOff + 64, AREG8(1));
  STAGE8B(kOff + 64, BREG8(1));
  kOff += 128;
  VMCNT4();
  BARRIER();
  READFRAGS8(0, afA, bfA);
  LGKMCNT0();
  BARRIER();

  for (int t = 0; t <= NT - 4; t += 2) {
    STAGE8A(kOff, AREG8(0));
    STAGE8B(kOff, BREG8(0));
    kOff += 64;
    VMCNT4();
    BARRIER();
    READFRAGS8(1, afB, bfB);
    MFMA8(afA, bfA);
    LGKMCNT0();
    BARRIER();
    STAGE8A(kOff, AREG8(1));
    STAGE8B(kOff, BREG8(1));
    kOff += 64;
    VMCNT4();
    BARRIER();
    READFRAGS8(0, afA, bfA);
    MFMA8(afB, bfB);
    LGKMCNT0();
    BARRIER();
  }
  VMCNT0();
  BARRIER();
  READFRAGS8(1, afB, bfB);
  MFMA8(afA, bfA);
  LGKMCNT0();
  MFMA8(afB, bfB);

  // ---- epilogue: descale, LDS transpose T[n][m] (slot-XOR), coalesced write
  {
    __syncthreads();
    const float DS = 1.f / 2048.f;  // 1/(16*128)
    const int crow = (l >> 4) * 4;
    const int ccol = l & 15;
    char* T = smem;  // 128 x 256 B = 32768
#pragma unroll
    for (int mi = 0; mi < 4; ++mi)
#pragma unroll
      for (int j = 0; j < 4; ++j) {
        int ml = mi * 32 + wr * 16 + crow;
        int nl = j * 32 + wc * 16 + ccol;
        bf16x4 v;
#pragma unroll
        for (int r = 0; r < 4; ++r) v[r] = (__bf16)(acc[mi][j][r] * DS);
        *(bf16x4*)(T + nl * 256 + ((ml * 2) ^ ((nl & 7) << 4))) = v;
      }
    __syncthreads();
    __bf16* dst = z ? S2 : S1;
    const int bA = m0 >> 6;
#pragma unroll
    for (int it = 0; it < 4; ++it) {
      int nl = (tid >> 3) + it * 32;
      int seg = tid & 7;
      int xorv = (nl & 7) << 4;
      const char* src = T + nl * 256;
      bf16x8 v0 = *(const bf16x8*)(src + ((seg * 32) ^ xorv));
      bf16x8 v1 = *(const bf16x8*)(src + ((seg * 32 + 16) ^ xorv));
      int b = bA + (seg >> 2);
      size_t o = ((size_t)b * NNODE + n0 + nl) * 64 + (seg & 3) * 16;
      *(bf16x8*)(dst + o) = v0;
      *(bf16x8*)(dst + o + 8) = v1;
    }
  }
#undef STAGE8A
#undef STAGE8B
#undef AREG8
#undef BREG8
}

// ---------------------------------------------------------------------------
// M28[i] = fp8(128 * (M2a[i] + M2b[i]))
__global__ __launch_bounds__(256) void combine_m2(const float* __restrict__ M2p,
                                                  unsigned char* __restrict__ M28) {
  const size_t NN2 = (size_t)NNODE * NNODE;
  size_t i = ((size_t)blockIdx.x * 256 + threadIdx.x) * 4;
  float4 a = *(const float4*)(M2p + i);
  float4 b = *(const float4*)(M2p + NN2 + i);
  const float SA = 128.f;
  int w0 = __builtin_amdgcn_cvt_pk_fp8_f32((a.x + b.x) * SA, (a.y + b.y) * SA, 0, false);
  w0 = __builtin_amdgcn_cvt_pk_fp8_f32((a.z + b.z) * SA, (a.w + b.w) * SA, w0, true);
  *(int*)(M28 + i) = w0;
}

// ---------------------------------------------------------------------------
// Gate linear GEMM: [65536 x 192] @ Wt^T, K=192, N=128, fused epilogues.
// MODE 0: cols 0-63 -> z=sigmoid -> zbuf(f32); cols 64-127 -> r ->
//         rx=(bf16)(r*hid) row-major AND fp8(16*rx)^T -> XT8out.
// MODE 1: cols 0-63 -> c=tanh -> out=(1-z)*hid+z*c (f32)
template <int MODE>
__global__ __launch_bounds__(256) void gemm_lin(const __bf16* __restrict__ Xp,
                                                const __bf16* __restrict__ S1,
                                                const __bf16* __restrict__ S2,
                                                const __bf16* __restrict__ Wt,
                                                const float* __restrict__ b0,
                                                const float* __restrict__ b1,
                                                const float* __restrict__ wpre,
                                                const float* __restrict__ wadp,
                                                const float* __restrict__ hid,
                                                float* __restrict__ zbuf,
                                                __bf16* __restrict__ rxout,
                                                unsigned char* __restrict__ XT8out,
                                                float* __restrict__ outp) {
  __shared__ __bf16 As[128 * 32];
  __shared__ __bf16 Bs[128 * 32];
  __shared__ char T[64 * 256];  // rx transpose staging (MODE 0)
  const int tid = threadIdx.x;
  const int wave = tid >> 6, lane = tid & 63;
  const int wr = wave >> 1, wc = wave & 1;
  const int m0 = blockIdx.x * 128;
  const int rowA = tid >> 2;
  const int colb = (tid & 3) * 16;
  const __bf16* srcs[3] = {Xp, S1, S2};
  char* asD0 = (char*)As + wave * 1024;
  char* asD1 = (char*)As + 4096 + wave * 1024;
  char* bsD0 = (char*)Bs + wave * 1024;
  char* bsD1 = (char*)Bs + 4096 + wave * 1024;

  f32x4 acc[4][4] = {};

#pragma unroll
  for (int kt = 0; kt < 6; ++kt) {
    const __bf16* Ab = srcs[kt >> 1];
    const char* aS0 = (const char*)(Ab + (size_t)(m0 + rowA) * 64) + (kt & 1) * 64 + colb;
    const char* aS1 = (const char*)(Ab + (size_t)(m0 + rowA + 64) * 64) + (kt & 1) * 64 + colb;
    const char* bS0 = (const char*)(Wt + (size_t)rowA * 192) + kt * 64 + colb;
    const char* bS1 = (const char*)(Wt + (size_t)(rowA + 64) * 192) + kt * 64 + colb;
    gload16(aS0, asD0);
    gload16(aS1, asD1);
    gload16(bS0, bsD0);
    gload16(bS1, bsD1);
    __syncthreads();
    bf16x8 af[4], bfr[4];
#pragma unroll
    for (int mi = 0; mi < 4; ++mi)
      af[mi] = *(const bf16x8*)((const char*)As +
               ((wr * 64 + mi * 16 + (lane & 15)) * 64 + (lane >> 4) * 16));
#pragma unroll
    for (int ni = 0; ni < 4; ++ni)
      bfr[ni] = *(const bf16x8*)((const char*)Bs +
               ((wc * 64 + ni * 16 + (lane & 15)) * 64 + (lane >> 4) * 16));
#pragma unroll
    for (int mi = 0; mi < 4; ++mi)
#pragma unroll
      for (int ni = 0; ni < 4; ++ni)
        acc[mi][ni] = __builtin_amdgcn_mfma_f32_16x16x32_bf16(af[mi], bfr[ni],
                                                              acc[mi][ni], 0, 0, 0);
    __syncthreads();
  }

  const float wp = *wpre, wa = *wadp;
  const float s = 2.f * wp + wa;
  const int crow = (lane >> 4) * 4;
  const int ccol = lane & 15;
#pragma unroll
  for (int mi = 0; mi < 4; ++mi)
#pragma unroll
    for (int ni = 0; ni < 4; ++ni) {
      int r0 = m0 + wr * 64 + mi * 16 + crow;
      int col = wc * 64 + ni * 16 + ccol;
      int cf = col & 63;
      if (MODE == 0) {
        if (col < 64) {
#pragma unroll
          for (int r = 0; r < 4; ++r) {
            int row = r0 + r;
            float g = acc[mi][ni][r] + s * b0[cf];
            zbuf[(size_t)row * 64 + cf] = 1.f / (1.f + __expf(-g));
          }
        } else {
          bf16x4 tv;
#pragma unroll
          for (int r = 0; r < 4; ++r) {
            int row = r0 + r;
            float g = acc[mi][ni][r] + s * b1[cf];
            float rv = 1.f / (1.f + __expf(-g));
            __bf16 rxv = (__bf16)(rv * hid[(size_t)row * 64 + cf]);
            rxout[(size_t)row * 64 + cf] = rxv;
            tv[r] = rxv;
          }
          int vl0 = wr * 64 + mi * 16 + crow;
          *(bf16x4*)(T + cf * 256 + ((vl0 * 2) ^ ((cf & 7) << 4))) = tv;
        }
      } else {
        if (col < 64) {
#pragma unroll
          for (int r = 0; r < 4; ++r) {
            int row = r0 + r;
            float g = acc[mi][ni][r] + s * b0[cf];
            float cv = 1.f - 2.f / (1.f + __expf(2.f * g));
            float zv = zbuf[(size_t)row * 64 + cf];
            float hv = hid[(size_t)row * 64 + cf];
            outp[(size_t)row * 64 + cf] = (1.f - zv) * hv + zv * cv;
          }
        }
      }
    }

  if (MODE == 0) {
    __syncthreads();
    const int b = m0 >> 11;
    const int v0 = m0 & 2047;
    const float SX = 16.f;
#pragma unroll
    for (int it = 0; it < 4; ++it) {
      int rr = it * 16 + (tid >> 4);
      int seg = tid & 15;
      bf16x8 v = *(const bf16x8*)(T + rr * 256 + ((seg * 16) ^ ((rr & 7) << 4)));
      int w0 = __builtin_amdgcn_cvt_pk_fp8_f32((float)v[0] * SX, (float)v[1] * SX, 0, false);
      w0 = __builtin_amdgcn_cvt_pk_fp8_f32((float)v[2] * SX, (float)v[3] * SX, w0, true);
      int w1 = __builtin_amdgcn_cvt_pk_fp8_f32((float)v[4] * SX, (float)v[5] * SX, 0, false);
      w1 = __builtin_amdgcn_cvt_pk_fp8_f32((float)v[6] * SX, (float)v[7] * SX, w1, true);
      int2 pk; pk.x = w0; pk.y = w1;
      *(int2*)(XT8out + ((size_t)(b * 64 + rr)) * NNODE + v0 + seg * 8) = pk;
    }
  }
}

// ---------------------------------------------------------------------------
extern "C" void kernel_launch(void* const* d_in, const int* in_sizes, int n_in,
                              void* d_out, int out_size, void* d_ws, size_t ws_size,
                              hipStream_t stream) {
  (void)in_sizes; (void)n_in; (void)out_size;
  const float* x    = (const float*)d_in[0];
  const float* A1   = (const float*)d_in[1];
  const float* A2   = (const float*)d_in[2];
  const float* E1   = (const float*)d_in[3];
  const float* E2   = (const float*)d_in[4];
  const float* Wz   = (const float*)d_in[5];
  const float* bz   = (const float*)d_in[6];
  const float* Wr   = (const float*)d_in[7];
  const float* br   = (const float*)d_in[8];
  const float* Wc   = (const float*)d_in[9];
  const float* bc   = (const float*)d_in[10];
  const float* wpre = (const float*)d_in[11];
  const float* wadp = (const float*)d_in[12];
  float* out = (float*)d_out;

  char* ws = (char*)d_ws;
  const size_t NN2 = (size_t)NNODE * NNODE;  // 4,194,304
  const size_t NN2B = NN2 * 2;               // bytes per bf16 slice
  __bf16* ADJ  = (__bf16*)(ws);                 // softmax out @ bf16 slices 0..3
  unsigned char* ADJ8  = (unsigned char*)(ws + 6 * NN2B);           // 6 fp8
  unsigned char* ADJT8 = (unsigned char*)(ws + 6 * NN2B + 6 * NN2); // 6 fp8
  __bf16* SC   = (__bf16*)(ws + 12 * NN2B);     // scores (4 slices), then:
  float*  M2p  = (float*)(ws + 12 * NN2B);      // f32 partials x2 = [12,16)
  unsigned char* M18 = (unsigned char*)(ws + 18 * NN2B);        // fp8
  unsigned char* M28 = (unsigned char*)(ws + 18 * NN2B + NN2);  // fp8
  unsigned char* XT8 = (unsigned char*)(ws + 20 * NN2B);        // fp8
  __bf16* xbf  = (__bf16*)(ws + 21 * NN2B);
  __bf16* rx   = (__bf16*)(ws + 22 * NN2B);
  __bf16* S1   = (__bf16*)(ws + 2 * NN2B);      // over ADJ slice 2 (dead post-prep)
  __bf16* S2   = (__bf16*)(ws + 3 * NN2B);      // over ADJ slice 3
  float*  zbuf = (float*)(ws + 4 * NN2B);       // over ADJ slices 4..5
  __bf16* E1p  = (__bf16*)(ws + 23 * NN2B);
  __bf16* E2p  = E1p + 4 * NNODE * 32;
  __bf16* Wzrt = E2p + 4 * NNODE * 32;
  __bf16* Wct  = Wzrt + 128 * 192;
  if (ws_size < 23 * NN2B + 2 * 4 * NNODE * 32 * 2 + 2 * 128 * 192 * 2) return;

  // --- adjacency construction (fused)
  prep_ew<<<224, 256, 0, stream>>>(E1, E2, Wz, Wr, Wc, wpre, wadp,
                                   E1p, E2p, Wzrt, Wct);
  score_gemm<<<dim3(16, 16, 4), 256, 0, stream>>>(E1p, E2p, SC);
  soft_tx<<<3072, 256, 0, stream>>>(SC, ADJ, x, XT8, xbf);
  prep_adj<<<dim3(32, 32), 256, 0, stream>>>(A1, A2, ADJ, ADJ8, ADJT8, M18,
                                             wpre, wadp);

  // --- M2 = sum_z w_z A_z^2 (fp8; 512 blocks, XCD-chunked)
  gemm_sq<<<dim3(16, 16, 2), 256, 32768, stream>>>(ADJ8, ADJT8, M2p);
  combine_m2<<<4096, 256, 0, stream>>>(M2p, M28);

  // --- stage 1: S1 = M1 x, S2 = M2 x (fp8, fused transposed epilogue)
  gemm_hop1s8<<<dim3(16, 16, 2), 256, 32768, stream>>>(XT8, M18, M28, S1, S2);
  gemm_lin<0><<<512, 256, 0, stream>>>(xbf, S1, S2, Wzrt, bz, br, wpre, wadp,
                                       x, zbuf, rx, XT8, nullptr);

  // --- stage 2: hops on r*x (XT8 holds fp8(16*rx)^T from gemm_lin<0>)
  gemm_hop1s8<<<dim3(16, 16, 2), 256, 32768, stream>>>(XT8, M18, M28, S1, S2);
  gemm_lin<1><<<512, 256, 0, stream>>>(rx, S1, S2, Wct, bc, nullptr, wpre, wadp,
                                       x, zbuf, nullptr, nullptr, out);
}